// Round 11
// baseline (1068.153 us; speedup 1.0000x reference)
//
#include <hip/hip_runtime.h>
#include <hip/hip_bf16.h>
#include <math.h>

namespace {

constexpr int BB=2, SS=1024, HH=1024, NH=16, NKV=4, DH=64;
constexpr int II=4096, EE=8;
constexpr int TT=BB*SS;
constexpr int QKV=1536;                 // merged projection width: 1024 q + 256 k + 256 v
constexpr float EPS=1e-5f;

typedef __bf16 bf16x8 __attribute__((ext_vector_type(8)));
typedef float f32x4 __attribute__((ext_vector_type(4)));

__device__ __forceinline__ unsigned short f2bf(float x){
  union { float f; unsigned u; } un; un.f = x;
  unsigned r = un.u + 0x7fffu + ((un.u>>16)&1u);
  return (unsigned short)(r>>16);
}
__device__ __forceinline__ float bfval(unsigned short h){
  union { unsigned u; float f; } r; r.u = ((unsigned)h)<<16; return r.f;
}
__device__ __forceinline__ void split2(float v, unsigned short& hi, unsigned short& lo){
  hi = f2bf(v);
  lo = f2bf(v - bfval(hi));
}

__device__ __forceinline__ void gl_lds16(const void* g, void* l){
  __builtin_amdgcn_global_load_lds(
    (const __attribute__((address_space(1))) unsigned int*)g,
    (__attribute__((address_space(3))) unsigned int*)l, 16, 0, 0);
}

__device__ __forceinline__ float gelu_tanh(float x){
  float x3 = x*x*x;
  return 0.5f*x*(1.f + tanhf(0.7978845608028654f*(x + 0.044715f*x3)));
}

// ---------------- RMSNorm: optional fp32 / bf16 / split outputs ----------------
__global__ void rmsnorm_kernel(const float* __restrict__ in, const float* __restrict__ scale,
                               float* __restrict__ outf, unsigned short* __restrict__ outb,
                               unsigned short* __restrict__ outh, unsigned short* __restrict__ outl){
  int row = blockIdx.x, tid = threadIdx.x;
  const float* x = in + (size_t)row*HH;
  float ss = 0.f;
  for (int i=tid;i<HH;i+=256){ float v=x[i]; ss+=v*v; }
  __shared__ float red[256];
  red[tid]=ss; __syncthreads();
  for (int s=128;s>0;s>>=1){ if(tid<s) red[tid]+=red[tid+s]; __syncthreads(); }
  float inv = rsqrtf(red[0]/(float)HH + EPS);
  for (int i=tid;i<HH;i+=256){
    float v = x[i]*inv*scale[i];
    size_t o = (size_t)row*HH+i;
    if (outf) outf[o]=v;
    if (outb) outb[o]=f2bf(v);
    if (outh){ unsigned short h,l; split2(v,h,l); outh[o]=h; outl[o]=l; }
  }
}

__global__ void add_kernel(const float* __restrict__ a, const float* __restrict__ b,
                           float* __restrict__ o, int n){
  int i = blockIdx.x*256 + threadIdx.x;
  if (i < n) o[i] = a[i] + b[i];
}

// ---------------- RoPE from merged proj buffer -> split bf16 planes ----------------
__global__ void rope_split_kernel(const float* __restrict__ x, int stride, int off,
                                  const int* __restrict__ pos_ids,
                                  unsigned short* __restrict__ oh, unsigned short* __restrict__ ol,
                                  int nheads){
  int idx = blockIdx.x*256 + threadIdx.x;
  int total = TT*nheads*32;
  if (idx >= total) return;
  int j = idx & 31;
  int hh = (idx>>5) % nheads;
  int t = idx / (32*nheads);
  float pos = (float)pos_ids[t];
  float inv_freq = powf(10000.f, -(float)j/32.f);
  float ang = pos * inv_freq;
  float s, c; sincosf(ang, &s, &c);
  const float* p = x + (size_t)t*stride + off + hh*DH;
  float x1 = p[j], x2 = p[j+32];
  float r1 = x1*c - x2*s;
  float r2 = x2*c + x1*s;
  size_t o = ((size_t)t*nheads + hh)*DH;
  unsigned short h1,l1,h2,l2;
  split2(r1,h1,l1); split2(r2,h2,l2);
  oh[o+j]=h1;    ol[o+j]=l1;
  oh[o+j+32]=h2; ol[o+j+32]=l2;
}

// ---------------- V transpose (from merged proj) -> split bf16 Vt[b][kvh][d][S] ----------------
__global__ __launch_bounds__(256) void vt_split_kernel(const float* __restrict__ src, int stride, int off,
    unsigned short* __restrict__ vth, unsigned short* __restrict__ vtl){
  int k0 = blockIdx.x*64;
  int kvh = blockIdx.y;
  int b = blockIdx.z;
  __shared__ float tile[64][65];
  int t = threadIdx.x;
  int c4 = (t&15)*4, gg = t>>4;
#pragma unroll
  for (int r=0;r<4;r++){
    int kk = gg + r*16;
    float4 v = *reinterpret_cast<const float4*>(src + (size_t)(b*SS+k0+kk)*stride + off + kvh*DH + c4);
    tile[kk][c4]=v.x; tile[kk][c4+1]=v.y; tile[kk][c4+2]=v.z; tile[kk][c4+3]=v.w;
  }
  __syncthreads();
#pragma unroll
  for (int r=0;r<4;r++){
    int dd = gg + r*16;
    ushort4 h4, l4v;
    split2(tile[c4  ][dd], h4.x, l4v.x);
    split2(tile[c4+1][dd], h4.y, l4v.y);
    split2(tile[c4+2][dd], h4.z, l4v.z);
    split2(tile[c4+3][dd], h4.w, l4v.w);
    size_t o = ((size_t)(b*NKV+kvh)*DH + dd)*SS + k0 + c4;
    *reinterpret_cast<ushort4*>(vth+o)=h4;
    *reinterpret_cast<ushort4*>(vtl+o)=l4v;
  }
}

// ---------------- MFMA flash attention (split-bf16, fp32-accurate) ----------------
__global__ __launch_bounds__(256) void attn_mfma(
    const unsigned short* __restrict__ qh, const unsigned short* __restrict__ ql,
    const unsigned short* __restrict__ khp, const unsigned short* __restrict__ klp,
    const unsigned short* __restrict__ vth, const unsigned short* __restrict__ vtl,
    const int* __restrict__ amask,
    unsigned short* __restrict__ ctxh, unsigned short* __restrict__ ctxl)
{
  int qb = blockIdx.x, h = blockIdx.y, b = blockIdx.z;
  int kvh = h >> 2;
  int tid = threadIdx.x;
  int w = tid >> 6, lane = tid & 63;
  int g = lane >> 4, l15 = lane & 15;

  __shared__ __align__(16) unsigned short Klh[64*64];
  __shared__ __align__(16) unsigned short Kll[64*64];
  __shared__ __align__(16) unsigned short Vlh[64*64];
  __shared__ __align__(16) unsigned short Vll[64*64];
  __shared__ __align__(16) unsigned short Pst[4][2][16*72];

  int q0w = qb*64 + w*16;

  bf16x8 qfh[2], qfl[2];
  {
    size_t qrow = ((size_t)(b*SS + q0w + l15)*NH + h)*DH;
#pragma unroll
    for (int ks=0; ks<2; ks++){
      qfh[ks] = *reinterpret_cast<const bf16x8*>(qh + qrow + ks*32 + g*8);
      qfl[ks] = *reinterpret_cast<const bf16x8*>(ql + qrow + ks*32 + g*8);
    }
  }

  f32x4 acc[4];
  float m_run[4], l_run[4];
#pragma unroll
  for (int i=0;i<4;i++){ acc[i]=f32x4{0,0,0,0}; m_run[i]=-1e30f; l_run[i]=0.f; }

  int nkv = qb + 1;
  for (int kblk=0; kblk<nkv; kblk++){
    int k0 = kblk*64;
    __syncthreads();
#pragma unroll
    for (int shot=0; shot<2; shot++){
      int a = shot*256 + tid;
      int row = a>>3, seg = a&7;
      int ss8 = (seg ^ (row&7))*8;
      int lo = row*64 + seg*8;
      size_t kg = ((size_t)(b*SS + k0 + row)*NKV + kvh)*DH + ss8;
      size_t vg = ((size_t)(b*NKV + kvh)*DH + row)*SS + k0 + ss8;
      gl_lds16(khp + kg, Klh + lo);
      gl_lds16(klp + kg, Kll + lo);
      gl_lds16(vth + vg, Vlh + lo);
      gl_lds16(vtl + vg, Vll + lo);
    }
    __syncthreads();

    f32x4 sf[4];
#pragma unroll
    for (int nf=0;nf<4;nf++) sf[nf]=f32x4{0,0,0,0};
#pragma unroll
    for (int ks=0; ks<2; ks++){
#pragma unroll
      for (int nf=0; nf<4; nf++){
        int krow = nf*16 + l15;
        int off = krow*64 + (((ks*4+g) ^ (krow&7))*8);
        bf16x8 bh = *reinterpret_cast<const bf16x8*>(Klh + off);
        bf16x8 bl = *reinterpret_cast<const bf16x8*>(Kll + off);
        sf[nf] = __builtin_amdgcn_mfma_f32_16x16x32_bf16(qfh[ks], bh, sf[nf],0,0,0);
        sf[nf] = __builtin_amdgcn_mfma_f32_16x16x32_bf16(qfh[ks], bl, sf[nf],0,0,0);
        sf[nf] = __builtin_amdgcn_mfma_f32_16x16x32_bf16(qfl[ks], bh, sf[nf],0,0,0);
      }
    }

    int am4[4];
#pragma unroll
    for (int nf=0;nf<4;nf++) am4[nf] = amask[b*SS + k0 + nf*16 + l15];
#pragma unroll
    for (int nf=0;nf<4;nf++){
      int k_abs = k0 + nf*16 + l15;
#pragma unroll
      for (int r=0;r<4;r++){
        float s = sf[nf][r]*0.125f;
        int q_abs = q0w + g*4 + r;
        if (k_abs > q_abs || am4[nf] <= 0) s = -1e9f;
        sf[nf][r] = s;
      }
    }

    float m_new[4], fsc[4];
#pragma unroll
    for (int r=0;r<4;r++){
      float v = fmaxf(fmaxf(sf[0][r],sf[1][r]), fmaxf(sf[2][r],sf[3][r]));
#pragma unroll
      for (int o=1;o<16;o<<=1) v = fmaxf(v, __shfl_xor(v,o));
      m_new[r] = fmaxf(m_run[r], v);
      fsc[r] = expf(m_run[r] - m_new[r]);
      m_run[r] = m_new[r];
    }

    unsigned short* Ph  = Pst[w][0];
    unsigned short* Plo = Pst[w][1];
    float rsum[4] = {0.f,0.f,0.f,0.f};
#pragma unroll
    for (int nf=0;nf<4;nf++){
#pragma unroll
      for (int r=0;r<4;r++){
        float p = expf(sf[nf][r] - m_new[r]);
        rsum[r] += p;
        unsigned short hi = f2bf(p);
        float lo = p - bfval(hi);
        Ph [(g*4+r)*72 + nf*16 + l15] = hi;
        Plo[(g*4+r)*72 + nf*16 + l15] = f2bf(lo);
      }
    }
#pragma unroll
    for (int r=0;r<4;r++){
#pragma unroll
      for (int o=1;o<16;o<<=1) rsum[r] += __shfl_xor(rsum[r],o);
      l_run[r] = l_run[r]*fsc[r] + rsum[r];
#pragma unroll
      for (int nf=0;nf<4;nf++) acc[nf][r] *= fsc[r];
    }

#pragma unroll
    for (int ks=0; ks<2; ks++){
      bf16x8 pa = *reinterpret_cast<const bf16x8*>(Ph  + l15*72 + ks*32 + g*8);
      bf16x8 pl = *reinterpret_cast<const bf16x8*>(Plo + l15*72 + ks*32 + g*8);
#pragma unroll
      for (int nf=0; nf<4; nf++){
        int drow = nf*16 + l15;
        int off = drow*64 + (((ks*4+g) ^ (drow&7))*8);
        bf16x8 vh = *reinterpret_cast<const bf16x8*>(Vlh + off);
        bf16x8 vl = *reinterpret_cast<const bf16x8*>(Vll + off);
        acc[nf] = __builtin_amdgcn_mfma_f32_16x16x32_bf16(pa, vh, acc[nf],0,0,0);
        acc[nf] = __builtin_amdgcn_mfma_f32_16x16x32_bf16(pa, vl, acc[nf],0,0,0);
        acc[nf] = __builtin_amdgcn_mfma_f32_16x16x32_bf16(pl, vh, acc[nf],0,0,0);
      }
    }
  }

#pragma unroll
  for (int r=0;r<4;r++){
    float inv = 1.f / l_run[r];
    size_t orow = ((size_t)(b*SS + q0w + g*4 + r)*NH + h)*DH;
#pragma unroll
    for (int nf=0;nf<4;nf++){
      float v = acc[nf][r]*inv;
      unsigned short hi,lo; split2(v,hi,lo);
      ctxh[orow + nf*16 + l15] = hi;
      ctxl[orow + nf*16 + l15] = lo;
    }
  }
}

// ---------------- MoE routing ----------------
__global__ void route_kernel(const float* __restrict__ x, const float* __restrict__ gw,
                             int* __restrict__ counts, int* __restrict__ lists,
                             float* __restrict__ cw){
  int t = blockIdx.x;
  int lane = threadIdx.x;
  float acc[EE];
#pragma unroll
  for (int e=0;e<EE;e++) acc[e]=0.f;
  for (int hh=lane; hh<HH; hh+=64){
    float xv = x[(size_t)t*HH + hh];
#pragma unroll
    for (int e=0;e<EE;e++) acc[e] += xv*gw[hh*EE+e];
  }
#pragma unroll
  for (int e=0;e<EE;e++){
#pragma unroll
    for (int off=1; off<64; off<<=1) acc[e] += __shfl_xor(acc[e], off);
  }
  if (lane==0){
    float m = acc[0];
    for (int e=1;e<EE;e++) m = fmaxf(m, acc[e]);
    float p[EE], s=0.f;
    for (int e=0;e<EE;e++){ p[e]=expf(acc[e]-m); s+=p[e]; }
    float invs = 1.f/s;
    for (int e=0;e<EE;e++) p[e]*=invs;
    int i1=0;
    for (int e=1;e<EE;e++) if (p[e]>p[i1]) i1=e;
    int i2 = (i1==0)?1:0;
    for (int e=0;e<EE;e++) if (e!=i1 && p[e]>p[i2]) i2=e;
    int pos = atomicAdd(&counts[i1],1);
    lists[i1*TT+pos]=t; cw[i1*TT+pos]=p[i1];
    pos = atomicAdd(&counts[i2],1);
    lists[i2*TT+pos]=t; cw[i2*TT+pos]=p[i2];
  }
}

// prefix over experts + slot-indexed gate weights; bases[EE] = total
__global__ void prefix_kernel(const int* __restrict__ c, int* __restrict__ b,
                              const float* __restrict__ cw, float* __restrict__ cw_slot){
  int lane = threadIdx.x;
  __shared__ int sb[EE+1];
  if (lane==0){
    int s=0;
    for (int e=0;e<EE;e++){ sb[e]=s; b[e]=s; s+=c[e]; }
    sb[EE]=s; b[EE]=s;
  }
  __syncthreads();
  for (int e=0;e<EE;e++){
    int cnt=c[e], base=sb[e];
    for (int i=lane;i<cnt;i+=64) cw_slot[base+i]=cw[e*TT+i];
  }
}

// ehb = bf16( gelu(tmp0) * tmp1 * cw_slot[row] )
__global__ void moe_combine(const unsigned short* __restrict__ t0,
                            const unsigned short* __restrict__ t1,
                            const float* __restrict__ cwslot,
                            const int* __restrict__ ntotp,
                            unsigned short* __restrict__ ehb){
  int row = blockIdx.x;
  if (row >= *ntotp) return;
  float c = cwslot[row];
  size_t base = (size_t)row*II;
  int tid = threadIdx.x;
  for (int c0 = tid*8; c0 < II; c0 += 256*8){
    ushort4 x0 = *reinterpret_cast<const ushort4*>(t0+base+c0);
    ushort4 x1 = *reinterpret_cast<const ushort4*>(t0+base+c0+4);
    ushort4 y0 = *reinterpret_cast<const ushort4*>(t1+base+c0);
    ushort4 y1 = *reinterpret_cast<const ushort4*>(t1+base+c0+4);
    ushort4 o0, o1;
    o0.x = f2bf(gelu_tanh(bfval(x0.x))*bfval(y0.x)*c);
    o0.y = f2bf(gelu_tanh(bfval(x0.y))*bfval(y0.y)*c);
    o0.z = f2bf(gelu_tanh(bfval(x0.z))*bfval(y0.z)*c);
    o0.w = f2bf(gelu_tanh(bfval(x0.w))*bfval(y0.w)*c);
    o1.x = f2bf(gelu_tanh(bfval(x1.x))*bfval(y1.x)*c);
    o1.y = f2bf(gelu_tanh(bfval(x1.y))*bfval(y1.y)*c);
    o1.z = f2bf(gelu_tanh(bfval(x1.z))*bfval(y1.z)*c);
    o1.w = f2bf(gelu_tanh(bfval(x1.w))*bfval(y1.w)*c);
    *reinterpret_cast<ushort4*>(ehb+base+c0)   = o0;
    *reinterpret_cast<ushort4*>(ehb+base+c0+4) = o1;
  }
}

// ---------------- transpose + fp32->bf16 (single plane) ----------------
__global__ __launch_bounds__(256) void transpose_cvt(const float* __restrict__ in,
    unsigned short* __restrict__ out, int K, int N){
  __shared__ float tile[64][65];
  int k0 = blockIdx.x*64, n0 = blockIdx.y*64;
  int t = threadIdx.x;
  int c4 = (t&15)*4, g = t>>4;
#pragma unroll
  for (int r=0;r<4;r++){
    int kk = g + r*16;
    float4 v = *reinterpret_cast<const float4*>(in + (size_t)(k0+kk)*N + n0 + c4);
    tile[kk][c4]=v.x; tile[kk][c4+1]=v.y; tile[kk][c4+2]=v.z; tile[kk][c4+3]=v.w;
  }
  __syncthreads();
#pragma unroll
  for (int r=0;r<4;r++){
    int nn = g + r*16;
    ushort4 o;
    o.x=f2bf(tile[c4][nn]);   o.y=f2bf(tile[c4+1][nn]);
    o.z=f2bf(tile[c4+2][nn]); o.w=f2bf(tile[c4+3][nn]);
    *reinterpret_cast<ushort4*>(out + (size_t)(n0+nn)*K + k0 + c4) = o;
  }
}

// ---------------- transpose + split hi/lo ----------------
__global__ __launch_bounds__(256) void transpose_cvt_split(const float* __restrict__ in,
    unsigned short* __restrict__ oh, unsigned short* __restrict__ ol, int K, int N){
  __shared__ float tile[64][65];
  int k0 = blockIdx.x*64, n0 = blockIdx.y*64;
  int t = threadIdx.x;
  int c4 = (t&15)*4, g = t>>4;
#pragma unroll
  for (int r=0;r<4;r++){
    int kk = g + r*16;
    float4 v = *reinterpret_cast<const float4*>(in + (size_t)(k0+kk)*N + n0 + c4);
    tile[kk][c4]=v.x; tile[kk][c4+1]=v.y; tile[kk][c4+2]=v.z; tile[kk][c4+3]=v.w;
  }
  __syncthreads();
#pragma unroll
  for (int r=0;r<4;r++){
    int nn = g + r*16;
    ushort4 h4, l4v;
    split2(tile[c4  ][nn], h4.x, l4v.x);
    split2(tile[c4+1][nn], h4.y, l4v.y);
    split2(tile[c4+2][nn], h4.z, l4v.z);
    split2(tile[c4+3][nn], h4.w, l4v.w);
    size_t o = (size_t)(n0+nn)*K + k0 + c4;
    *reinterpret_cast<ushort4*>(oh + o) = h4;
    *reinterpret_cast<ushort4*>(ol + o) = l4v;
  }
}

// ---------------- split-bf16 3-term MFMA GEMM, double-buffered pipeline ----------------
__global__ __launch_bounds__(256,2) void mgemm_split(
    const unsigned short* __restrict__ Ah, const unsigned short* __restrict__ Alo,
    const unsigned short* __restrict__ Bh, const unsigned short* __restrict__ Blo,
    float* __restrict__ Cf, int N, int K)
{
  int row0 = blockIdx.x*128, col0 = blockIdx.y*128;
  __shared__ __align__(16) unsigned short lds[32768];   // 2 bufs x 4 planes x 4096

  int t = threadIdx.x;
  int lane = t&63, w = t>>6, wr = w>>1, wc = w&1;
  int sr = t>>2, seg = t&3;

  f32x4 acc[4][4];
#pragma unroll
  for (int m=0;m<4;m++)
#pragma unroll
    for (int n=0;n<4;n++) acc[m][n]=f32x4{0,0,0,0};

  int l15 = lane&15, l4 = lane>>4;

  auto stage = [&](int buf, int k0){
    unsigned short* Lb = lds + buf*16384;
#pragma unroll
    for (int i=0;i<2;i++){
      int ldso = (sr + i*64)*32 + seg*8;
      size_t ar = (size_t)(row0 + sr + i*64);
      size_t br = (size_t)(col0 + sr + i*64);
      gl_lds16(Ah  + ar*K + k0 + seg*8, Lb +         ldso);
      gl_lds16(Alo + ar*K + k0 + seg*8, Lb + 4096  + ldso);
      gl_lds16(Bh  + br*K + k0 + seg*8, Lb + 8192  + ldso);
      gl_lds16(Blo + br*K + k0 + seg*8, Lb + 12288 + ldso);
    }
  };

  stage(0, 0);
  __syncthreads();
  int cur = 0;
  int NIT = K/32;
  for (int it=0; it<NIT; it++){
    if (it+1 < NIT) stage(cur^1, (it+1)*32);
    const unsigned short* Lb = lds + cur*16384;
    const bf16x8* Aph = reinterpret_cast<const bf16x8*>(Lb +         (wr*64 + l15)*32 + l4*8);
    const bf16x8* Apl = reinterpret_cast<const bf16x8*>(Lb + 4096  + (wr*64 + l15)*32 + l4*8);
    const bf16x8* Bph = reinterpret_cast<const bf16x8*>(Lb + 8192  + (wc*64 + l15)*32 + l4*8);
    const bf16x8* Bpl = reinterpret_cast<const bf16x8*>(Lb + 12288 + (wc*64 + l15)*32 + l4*8);
    bf16x8 ah[4], al[4], bh[4], bl[4];
#pragma unroll
    for (int m=0;m<4;m++){ ah[m]=Aph[m*64]; al[m]=Apl[m*64]; }
#pragma unroll
    for (int n=0;n<4;n++){ bh[n]=Bph[n*64]; bl[n]=Bpl[n*64]; }
#pragma unroll
    for (int m=0;m<4;m++)
#pragma unroll
      for (int n=0;n<4;n++){
        acc[m][n] = __builtin_amdgcn_mfma_f32_16x16x32_bf16(ah[m], bh[n], acc[m][n], 0,0,0);
        acc[m][n] = __builtin_amdgcn_mfma_f32_16x16x32_bf16(ah[m], bl[n], acc[m][n], 0,0,0);
        acc[m][n] = __builtin_amdgcn_mfma_f32_16x16x32_bf16(al[m], bh[n], acc[m][n], 0,0,0);
      }
    __syncthreads();
    cur ^= 1;
  }

#pragma unroll
  for (int m=0;m<4;m++){
    int rb = wr*64 + m*16 + l4*4;
#pragma unroll
    for (int n=0;n<4;n++){
      int col = col0 + wc*64 + n*16 + l15;
#pragma unroll
      for (int r=0;r<4;r++){
        int row = row0 + rb + r;
        Cf[(size_t)row*N + col] = acc[m][n][r];
      }
    }
  }
}

// ---------------- bf16 MFMA GEMM (MoE expert path) ----------------
// BK=32, 3-buffer depth-2 pipeline with counted vmcnt + raw s_barrier (T3+T4 minimum).
// Per-wave: 4 gl_lds16 per stage; steady-state wait vmcnt(4) -> current buffer landed,
// next stage's 4 loads still in flight across the barrier. Restaged buffer was last
// read >=1 barrier ago (reads completed before that wave's MFMAs issued).
// MODE 1 (up): A rows via rowlist; blockIdx.y parity selects B0 (w_in) vs B1 (w_v);
//              writes bf16 tmp plane at slot rows.
// MODE 2 (down): A rows = ehb[slot+row]; blockIdx.y = col tile (8) | K-section (4);
//                atomicAdd Cf[rowlist[row], col]
template<int MODE>
__global__ __launch_bounds__(256,3) void mgemm(
    const unsigned short* __restrict__ A, const unsigned short* __restrict__ B0b,
    const unsigned short* __restrict__ B1b, size_t bstride,
    float* __restrict__ Cf, unsigned short* __restrict__ Cb0, unsigned short* __restrict__ Cb1,
    int N, int K,
    const int* __restrict__ listb,
    const int* __restrict__ countb, const int* __restrict__ basep)
{
  int e = blockIdx.z;
  int M = countb[e];
  int row0 = blockIdx.x*128;
  if (row0 >= M) return;
  int which = 0, col0, kbase = 0, KL = K;
  const unsigned short* B;
  if (MODE==1){
    which = blockIdx.y & 1;
    col0 = (blockIdx.y >> 1)*128;
    B = (which ? B1b : B0b) + bstride*e;
  } else {
    col0 = (blockIdx.y & 7)*128;
    kbase = (blockIdx.y >> 3)*(K/4);
    KL = K/4;
    B = B0b + bstride*e;
  }
  int slot = basep ? basep[e] : 0;
  const int* rowlist = listb + e*TT;

  // 3 bufs x (A[128][32] + B[128][32]) bf16 = 48 KB -> 3 blocks/CU
  __shared__ __align__(16) unsigned short lds[3][2][4096];

  int t = threadIdx.x;
  int lane = t&63, w = t>>6, wr = w>>1, wc = w&1;
  int sr = t>>2, seg = t&3;

  size_t arow[2], brow[2];
#pragma unroll
  for (int i=0;i<2;i++){
    int r = row0 + sr + i*64;
    int rc = (r < M) ? r : (M-1);
    if (MODE==1) arow[i] = (size_t)rowlist[rc];
    else         arow[i] = (size_t)(slot + rc);
    brow[i] = (size_t)(col0 + sr + i*64);
  }

  f32x4 acc[4][4];
#pragma unroll
  for (int m=0;m<4;m++)
#pragma unroll
    for (int n=0;n<4;n++) acc[m][n]=f32x4{0,0,0,0};

  int l15 = lane&15, l4 = lane>>4;

  auto stage = [&](int buf, int k0){
#pragma unroll
    for (int i=0;i<2;i++){
      int ldso = (sr + i*64)*32 + seg*8;
      gl_lds16(A + arow[i]*K + kbase + k0 + seg*8, &lds[buf][0][0] + ldso);
      gl_lds16(B + brow[i]*K + kbase + k0 + seg*8, &lds[buf][1][0] + ldso);
    }
  };

  int NIT = KL/32;
  stage(0, 0);
  if (NIT > 1) stage(1, 32);

  for (int it=0; it<NIT; it++){
    // wait for THIS wave's loads of buf[it] (4 oldest); next stage's 4 stay in flight.
    if (it+1 < NIT) asm volatile("s_waitcnt vmcnt(4)" ::: "memory");
    else            asm volatile("s_waitcnt vmcnt(0)" ::: "memory");
    __builtin_amdgcn_s_barrier();     // now buf[it] complete for ALL waves
    if (it+2 < NIT) stage((it+2)%3, (it+2)*32);

    int cb = it%3;
    const unsigned short* La = &lds[cb][0][0];
    const unsigned short* Lb = &lds[cb][1][0];
    bf16x8 af[4], bf[4];
#pragma unroll
    for (int m=0;m<4;m++)
      af[m] = *reinterpret_cast<const bf16x8*>(La + (wr*64 + m*16 + l15)*32 + l4*8);
#pragma unroll
    for (int n=0;n<4;n++)
      bf[n] = *reinterpret_cast<const bf16x8*>(Lb + (wc*64 + n*16 + l15)*32 + l4*8);
#pragma unroll
    for (int m=0;m<4;m++)
#pragma unroll
      for (int n=0;n<4;n++)
        acc[m][n] = __builtin_amdgcn_mfma_f32_16x16x32_bf16(af[m], bf[n], acc[m][n], 0,0,0);
  }

  unsigned short* Cb = which ? Cb1 : Cb0;
#pragma unroll
  for (int m=0;m<4;m++){
    int rb = wr*64 + m*16 + l4*4;
#pragma unroll
    for (int n=0;n<4;n++){
      int col = col0 + wc*64 + n*16 + l15;
#pragma unroll
      for (int r=0;r<4;r++){
        int row = row0 + rb + r;
        if (row >= M) continue;
        float v = acc[m][n][r];
        if (MODE==1){
          Cb[(size_t)(slot+row)*N + col] = f2bf(v);
        } else {
          atomicAdd(&Cf[(size_t)rowlist[row]*N + col], v);
        }
      }
    }
  }
}

} // namespace

extern "C" void kernel_launch(void* const* d_in, const int* in_sizes, int n_in,
                              void* d_out, int out_size, void* d_ws, size_t ws_size,
                              hipStream_t stream) {
  const float* hidden = (const float*)d_in[0];
  const int*   mask   = (const int*)d_in[1];
  const int*   pos    = (const int*)d_in[2];
  const float* q_w    = (const float*)d_in[3];
  const float* k_w    = (const float*)d_in[4];
  const float* v_w    = (const float*)d_in[5];
  const float* o_w    = (const float*)d_in[6];
  const float* pre_attn_scale  = (const float*)d_in[7];
  const float* post_attn_scale = (const float*)d_in[8];
  const float* pre_moe_scale   = (const float*)d_in[9];
  const float* post_moe_scale  = (const float*)d_in[10];
  const float* gate_w = (const float*)d_in[11];
  const float* w_in   = (const float*)d_in[12];
  const float* w_v    = (const float*)d_in[13];
  const float* w_out  = (const float*)d_in[14];
  float* out = (float*)d_out;

  char* base = (char*)d_ws;
  auto carve = [&](size_t bytes)->char*{
    char* r = base; base += (bytes + 255) & ~(size_t)255; return r;
  };
  float* hn  = (float*)carve((size_t)TT*HH*4);
  unsigned short* hnb = (unsigned short*)carve((size_t)TT*HH*2);
  unsigned short* hnh = (unsigned short*)carve((size_t)TT*HH*2);
  unsigned short* hnl = (unsigned short*)carve((size_t)TT*HH*2);
  float* qkvb = (float*)carve((size_t)TT*QKV*4);
  unsigned short* qsh = (unsigned short*)carve((size_t)TT*NH*DH*2);
  unsigned short* qsl = (unsigned short*)carve((size_t)TT*NH*DH*2);
  unsigned short* ksh = (unsigned short*)carve((size_t)TT*NKV*DH*2);
  unsigned short* ksl = (unsigned short*)carve((size_t)TT*NKV*DH*2);
  unsigned short* vth = (unsigned short*)carve((size_t)TT*NKV*DH*2);
  unsigned short* vtl = (unsigned short*)carve((size_t)TT*NKV*DH*2);
  unsigned short* ctxh = (unsigned short*)carve((size_t)TT*NH*DH*2);
  unsigned short* ctxl = (unsigned short*)carve((size_t)TT*NH*DH*2);
  float* ao  = (float*)carve((size_t)TT*HH*4);
  float* xb  = (float*)carve((size_t)TT*HH*4);
  float* moe = (float*)carve((size_t)TT*HH*4);
  float* cw  = (float*)carve((size_t)EE*TT*4);
  float* cw_slot = (float*)carve((size_t)2*TT*4);
  int* counts = (int*)carve(64*4);
  int* bases  = (int*)carve(64*4);
  int* lists  = (int*)carve((size_t)EE*TT*4);
  unsigned short* qkvwTh = (unsigned short*)carve((size_t)QKV*HH*2);
  unsigned short* qkvwTl = (unsigned short*)carve((size_t)QKV*HH*2);
  unsigned short* owTh = (unsigned short*)carve((size_t)NH*DH*HH*2);
  unsigned short* owTl = (unsigned short*)carve((size_t)NH*DH*HH*2);
  unsigned short* ehb   = (unsigned short*)carve((size_t)2*TT*II*2);
  unsigned short* tmp0  = (unsigned short*)carve((size_t)2*TT*II*2);
  unsigned short* tmp1  = (unsigned short*)carve((size_t)2*TT*II*2);
  unsigned short* winT  = (unsigned short*)carve((size_t)EE*II*HH*2);
  unsigned short* wvT   = (unsigned short*)carve((size_t)EE*II*HH*2);
  unsigned short* woutT = (unsigned short*)carve((size_t)EE*HH*II*2);
  size_t estride = (size_t)II*HH;

  // ---- attention block (split-bf16, fp32-accurate) ----
  rmsnorm_kernel<<<TT,256,0,stream>>>(hidden, pre_attn_scale, nullptr, nullptr, hnh, hnl);
  // merged qkv weight transpose: [1536][1024] hi/lo
  transpose_cvt_split<<<dim3(16,16),256,0,stream>>>(q_w, qkvwTh, qkvwTl, HH, NH*DH);
  transpose_cvt_split<<<dim3(16,4), 256,0,stream>>>(k_w, qkvwTh + (size_t)1024*HH, qkvwTl + (size_t)1024*HH, HH, NKV*DH);
  transpose_cvt_split<<<dim3(16,4), 256,0,stream>>>(v_w, qkvwTh + (size_t)1280*HH, qkvwTl + (size_t)1280*HH, HH, NKV*DH);
  transpose_cvt_split<<<dim3(16,16),256,0,stream>>>(o_w, owTh, owTl, NH*DH, HH);

  mgemm_split<<<dim3(16,QKV/128),256,0,stream>>>(hnh, hnl, qkvwTh, qkvwTl, qkvb, QKV, HH);

  rope_split_kernel<<<(TT*NH*32+255)/256,256,0,stream>>>(qkvb, QKV, 0, pos, qsh, qsl, NH);
  rope_split_kernel<<<(TT*NKV*32+255)/256,256,0,stream>>>(qkvb, QKV, 1024, pos, ksh, ksl, NKV);
  vt_split_kernel<<<dim3(SS/64,NKV,BB),256,0,stream>>>(qkvb, QKV, 1280, vth, vtl);

  attn_mfma<<<dim3(SS/64,NH,BB),256,0,stream>>>(qsh, qsl, ksh, ksl, vth, vtl, mask, ctxh, ctxl);

  mgemm_split<<<dim3(16,HH/128),256,0,stream>>>(ctxh, ctxl, owTh, owTl, ao, HH, NH*DH);
  rmsnorm_kernel<<<TT,256,0,stream>>>(ao, post_attn_scale, ao, nullptr, nullptr, nullptr);
  add_kernel<<<(TT*HH)/256,256,0,stream>>>(hidden, ao, xb, TT*HH);

  // ---- MoE block (routing fp32, experts bf16) ----
  rmsnorm_kernel<<<TT,256,0,stream>>>(xb, pre_moe_scale, hn, hnb, nullptr, nullptr);
  hipMemsetAsync(counts, 0, 64*sizeof(int), stream);
  hipMemsetAsync(moe, 0, (size_t)TT*HH*sizeof(float), stream);
  route_kernel<<<TT,64,0,stream>>>(hn, gate_w, counts, lists, cw);
  prefix_kernel<<<1,64,0,stream>>>(counts, bases, cw, cw_slot);

  for (int e=0;e<EE;e++){
    transpose_cvt<<<dim3(16,64),256,0,stream>>>(w_in + (size_t)e*HH*II, winT + (size_t)e*estride, HH, II);
    transpose_cvt<<<dim3(16,64),256,0,stream>>>(w_v  + (size_t)e*HH*II, wvT  + (size_t)e*estride, HH, II);
    transpose_cvt<<<dim3(64,16),256,0,stream>>>(w_out+ (size_t)e*II*HH, woutT+ (size_t)e*estride, II, HH);
  }

  // up: 128x128 tiles, BK=32, counted-vmcnt pipeline; y = plane parity | 32 col tiles
  mgemm<1><<<dim3(16,(2*II)/128,EE),256,0,stream>>>(hnb, winT, wvT, estride, nullptr, tmp0, tmp1,
      II, HH, lists, counts, bases);
  moe_combine<<<2*TT,256,0,stream>>>(tmp0, tmp1, cw_slot, bases+EE, ehb);
  // down: 128x128 tiles, BK=32, K-split x4; y = 8 col tiles | 4 K-sections
  mgemm<2><<<dim3(16,(HH/128)*4,EE),256,0,stream>>>(ehb, woutT, nullptr, estride, moe, nullptr, nullptr,
      HH, II, lists, counts, bases);

  rmsnorm_kernel<<<TT,256,0,stream>>>(moe, post_moe_scale, moe, nullptr, nullptr, nullptr);
  add_kernel<<<(TT*HH)/256,256,0,stream>>>(xb, moe, out, TT*HH);
}

// Round 12
// 679.039 us; speedup vs baseline: 1.5730x; 1.5730x over previous
//
#include <hip/hip_runtime.h>
#include <hip/hip_bf16.h>
#include <math.h>

namespace {

constexpr int BB=2, SS=1024, HH=1024, NH=16, NKV=4, DH=64;
constexpr int II=4096, EE=8;
constexpr int TT=BB*SS;
constexpr int QKV=1536;                 // merged projection width: 1024 q + 256 k + 256 v
constexpr float EPS=1e-5f;

typedef __bf16 bf16x8 __attribute__((ext_vector_type(8)));
typedef float f32x4 __attribute__((ext_vector_type(4)));

__device__ __forceinline__ unsigned short f2bf(float x){
  union { float f; unsigned u; } un; un.f = x;
  unsigned r = un.u + 0x7fffu + ((un.u>>16)&1u);
  return (unsigned short)(r>>16);
}
__device__ __forceinline__ float bfval(unsigned short h){
  union { unsigned u; float f; } r; r.u = ((unsigned)h)<<16; return r.f;
}
__device__ __forceinline__ void split2(float v, unsigned short& hi, unsigned short& lo){
  hi = f2bf(v);
  lo = f2bf(v - bfval(hi));
}

__device__ __forceinline__ void gl_lds16(const void* g, void* l){
  __builtin_amdgcn_global_load_lds(
    (const __attribute__((address_space(1))) unsigned int*)g,
    (__attribute__((address_space(3))) unsigned int*)l, 16, 0, 0);
}

__device__ __forceinline__ float gelu_tanh(float x){
  float x3 = x*x*x;
  return 0.5f*x*(1.f + tanhf(0.7978845608028654f*(x + 0.044715f*x3)));
}

// ---------------- RMSNorm: optional fp32 / bf16 / split outputs ----------------
__global__ void rmsnorm_kernel(const float* __restrict__ in, const float* __restrict__ scale,
                               float* __restrict__ outf, unsigned short* __restrict__ outb,
                               unsigned short* __restrict__ outh, unsigned short* __restrict__ outl){
  int row = blockIdx.x, tid = threadIdx.x;
  const float* x = in + (size_t)row*HH;
  float ss = 0.f;
  for (int i=tid;i<HH;i+=256){ float v=x[i]; ss+=v*v; }
  __shared__ float red[256];
  red[tid]=ss; __syncthreads();
  for (int s=128;s>0;s>>=1){ if(tid<s) red[tid]+=red[tid+s]; __syncthreads(); }
  float inv = rsqrtf(red[0]/(float)HH + EPS);
  for (int i=tid;i<HH;i+=256){
    float v = x[i]*inv*scale[i];
    size_t o = (size_t)row*HH+i;
    if (outf) outf[o]=v;
    if (outb) outb[o]=f2bf(v);
    if (outh){ unsigned short h,l; split2(v,h,l); outh[o]=h; outl[o]=l; }
  }
}

__global__ void add_kernel(const float* __restrict__ a, const float* __restrict__ b,
                           float* __restrict__ o, int n){
  int i = blockIdx.x*256 + threadIdx.x;
  if (i < n) o[i] = a[i] + b[i];
}

// ---------------- RoPE from merged proj buffer -> split bf16 planes ----------------
__global__ void rope_split_kernel(const float* __restrict__ x, int stride, int off,
                                  const int* __restrict__ pos_ids,
                                  unsigned short* __restrict__ oh, unsigned short* __restrict__ ol,
                                  int nheads){
  int idx = blockIdx.x*256 + threadIdx.x;
  int total = TT*nheads*32;
  if (idx >= total) return;
  int j = idx & 31;
  int hh = (idx>>5) % nheads;
  int t = idx / (32*nheads);
  float pos = (float)pos_ids[t];
  float inv_freq = powf(10000.f, -(float)j/32.f);
  float ang = pos * inv_freq;
  float s, c; sincosf(ang, &s, &c);
  const float* p = x + (size_t)t*stride + off + hh*DH;
  float x1 = p[j], x2 = p[j+32];
  float r1 = x1*c - x2*s;
  float r2 = x2*c + x1*s;
  size_t o = ((size_t)t*nheads + hh)*DH;
  unsigned short h1,l1,h2,l2;
  split2(r1,h1,l1); split2(r2,h2,l2);
  oh[o+j]=h1;    ol[o+j]=l1;
  oh[o+j+32]=h2; ol[o+j+32]=l2;
}

// ---------------- V transpose (from merged proj) -> split bf16 Vt[b][kvh][d][S] ----------------
__global__ __launch_bounds__(256) void vt_split_kernel(const float* __restrict__ src, int stride, int off,
    unsigned short* __restrict__ vth, unsigned short* __restrict__ vtl){
  int k0 = blockIdx.x*64;
  int kvh = blockIdx.y;
  int b = blockIdx.z;
  __shared__ float tile[64][65];
  int t = threadIdx.x;
  int c4 = (t&15)*4, gg = t>>4;
#pragma unroll
  for (int r=0;r<4;r++){
    int kk = gg + r*16;
    float4 v = *reinterpret_cast<const float4*>(src + (size_t)(b*SS+k0+kk)*stride + off + kvh*DH + c4);
    tile[kk][c4]=v.x; tile[kk][c4+1]=v.y; tile[kk][c4+2]=v.z; tile[kk][c4+3]=v.w;
  }
  __syncthreads();
#pragma unroll
  for (int r=0;r<4;r++){
    int dd = gg + r*16;
    ushort4 h4, l4v;
    split2(tile[c4  ][dd], h4.x, l4v.x);
    split2(tile[c4+1][dd], h4.y, l4v.y);
    split2(tile[c4+2][dd], h4.z, l4v.z);
    split2(tile[c4+3][dd], h4.w, l4v.w);
    size_t o = ((size_t)(b*NKV+kvh)*DH + dd)*SS + k0 + c4;
    *reinterpret_cast<ushort4*>(vth+o)=h4;
    *reinterpret_cast<ushort4*>(vtl+o)=l4v;
  }
}

// ---------------- MFMA flash attention (split-bf16, fp32-accurate) ----------------
__global__ __launch_bounds__(256) void attn_mfma(
    const unsigned short* __restrict__ qh, const unsigned short* __restrict__ ql,
    const unsigned short* __restrict__ khp, const unsigned short* __restrict__ klp,
    const unsigned short* __restrict__ vth, const unsigned short* __restrict__ vtl,
    const int* __restrict__ amask,
    unsigned short* __restrict__ ctxh, unsigned short* __restrict__ ctxl)
{
  int qb = blockIdx.x, h = blockIdx.y, b = blockIdx.z;
  int kvh = h >> 2;
  int tid = threadIdx.x;
  int w = tid >> 6, lane = tid & 63;
  int g = lane >> 4, l15 = lane & 15;

  __shared__ __align__(16) unsigned short Klh[64*64];
  __shared__ __align__(16) unsigned short Kll[64*64];
  __shared__ __align__(16) unsigned short Vlh[64*64];
  __shared__ __align__(16) unsigned short Vll[64*64];
  __shared__ __align__(16) unsigned short Pst[4][2][16*72];

  int q0w = qb*64 + w*16;

  bf16x8 qfh[2], qfl[2];
  {
    size_t qrow = ((size_t)(b*SS + q0w + l15)*NH + h)*DH;
#pragma unroll
    for (int ks=0; ks<2; ks++){
      qfh[ks] = *reinterpret_cast<const bf16x8*>(qh + qrow + ks*32 + g*8);
      qfl[ks] = *reinterpret_cast<const bf16x8*>(ql + qrow + ks*32 + g*8);
    }
  }

  f32x4 acc[4];
  float m_run[4], l_run[4];
#pragma unroll
  for (int i=0;i<4;i++){ acc[i]=f32x4{0,0,0,0}; m_run[i]=-1e30f; l_run[i]=0.f; }

  int nkv = qb + 1;
  for (int kblk=0; kblk<nkv; kblk++){
    int k0 = kblk*64;
    __syncthreads();
#pragma unroll
    for (int shot=0; shot<2; shot++){
      int a = shot*256 + tid;
      int row = a>>3, seg = a&7;
      int ss8 = (seg ^ (row&7))*8;
      int lo = row*64 + seg*8;
      size_t kg = ((size_t)(b*SS + k0 + row)*NKV + kvh)*DH + ss8;
      size_t vg = ((size_t)(b*NKV + kvh)*DH + row)*SS + k0 + ss8;
      gl_lds16(khp + kg, Klh + lo);
      gl_lds16(klp + kg, Kll + lo);
      gl_lds16(vth + vg, Vlh + lo);
      gl_lds16(vtl + vg, Vll + lo);
    }
    __syncthreads();

    f32x4 sf[4];
#pragma unroll
    for (int nf=0;nf<4;nf++) sf[nf]=f32x4{0,0,0,0};
#pragma unroll
    for (int ks=0; ks<2; ks++){
#pragma unroll
      for (int nf=0; nf<4; nf++){
        int krow = nf*16 + l15;
        int off = krow*64 + (((ks*4+g) ^ (krow&7))*8);
        bf16x8 bh = *reinterpret_cast<const bf16x8*>(Klh + off);
        bf16x8 bl = *reinterpret_cast<const bf16x8*>(Kll + off);
        sf[nf] = __builtin_amdgcn_mfma_f32_16x16x32_bf16(qfh[ks], bh, sf[nf],0,0,0);
        sf[nf] = __builtin_amdgcn_mfma_f32_16x16x32_bf16(qfh[ks], bl, sf[nf],0,0,0);
        sf[nf] = __builtin_amdgcn_mfma_f32_16x16x32_bf16(qfl[ks], bh, sf[nf],0,0,0);
      }
    }

    int am4[4];
#pragma unroll
    for (int nf=0;nf<4;nf++) am4[nf] = amask[b*SS + k0 + nf*16 + l15];
#pragma unroll
    for (int nf=0;nf<4;nf++){
      int k_abs = k0 + nf*16 + l15;
#pragma unroll
      for (int r=0;r<4;r++){
        float s = sf[nf][r]*0.125f;
        int q_abs = q0w + g*4 + r;
        if (k_abs > q_abs || am4[nf] <= 0) s = -1e9f;
        sf[nf][r] = s;
      }
    }

    float m_new[4], fsc[4];
#pragma unroll
    for (int r=0;r<4;r++){
      float v = fmaxf(fmaxf(sf[0][r],sf[1][r]), fmaxf(sf[2][r],sf[3][r]));
#pragma unroll
      for (int o=1;o<16;o<<=1) v = fmaxf(v, __shfl_xor(v,o));
      m_new[r] = fmaxf(m_run[r], v);
      fsc[r] = expf(m_run[r] - m_new[r]);
      m_run[r] = m_new[r];
    }

    unsigned short* Ph  = Pst[w][0];
    unsigned short* Plo = Pst[w][1];
    float rsum[4] = {0.f,0.f,0.f,0.f};
#pragma unroll
    for (int nf=0;nf<4;nf++){
#pragma unroll
      for (int r=0;r<4;r++){
        float p = expf(sf[nf][r] - m_new[r]);
        rsum[r] += p;
        unsigned short hi = f2bf(p);
        float lo = p - bfval(hi);
        Ph [(g*4+r)*72 + nf*16 + l15] = hi;
        Plo[(g*4+r)*72 + nf*16 + l15] = f2bf(lo);
      }
    }
#pragma unroll
    for (int r=0;r<4;r++){
#pragma unroll
      for (int o=1;o<16;o<<=1) rsum[r] += __shfl_xor(rsum[r],o);
      l_run[r] = l_run[r]*fsc[r] + rsum[r];
#pragma unroll
      for (int nf=0;nf<4;nf++) acc[nf][r] *= fsc[r];
    }

#pragma unroll
    for (int ks=0; ks<2; ks++){
      bf16x8 pa = *reinterpret_cast<const bf16x8*>(Ph  + l15*72 + ks*32 + g*8);
      bf16x8 pl = *reinterpret_cast<const bf16x8*>(Plo + l15*72 + ks*32 + g*8);
#pragma unroll
      for (int nf=0; nf<4; nf++){
        int drow = nf*16 + l15;
        int off = drow*64 + (((ks*4+g) ^ (drow&7))*8);
        bf16x8 vh = *reinterpret_cast<const bf16x8*>(Vlh + off);
        bf16x8 vl = *reinterpret_cast<const bf16x8*>(Vll + off);
        acc[nf] = __builtin_amdgcn_mfma_f32_16x16x32_bf16(pa, vh, acc[nf],0,0,0);
        acc[nf] = __builtin_amdgcn_mfma_f32_16x16x32_bf16(pa, vl, acc[nf],0,0,0);
        acc[nf] = __builtin_amdgcn_mfma_f32_16x16x32_bf16(pl, vh, acc[nf],0,0,0);
      }
    }
  }

#pragma unroll
  for (int r=0;r<4;r++){
    float inv = 1.f / l_run[r];
    size_t orow = ((size_t)(b*SS + q0w + g*4 + r)*NH + h)*DH;
#pragma unroll
    for (int nf=0;nf<4;nf++){
      float v = acc[nf][r]*inv;
      unsigned short hi,lo; split2(v,hi,lo);
      ctxh[orow + nf*16 + l15] = hi;
      ctxl[orow + nf*16 + l15] = lo;
    }
  }
}

// ---------------- MoE routing ----------------
__global__ void route_kernel(const float* __restrict__ x, const float* __restrict__ gw,
                             int* __restrict__ counts, int* __restrict__ lists,
                             float* __restrict__ cw){
  int t = blockIdx.x;
  int lane = threadIdx.x;
  float acc[EE];
#pragma unroll
  for (int e=0;e<EE;e++) acc[e]=0.f;
  for (int hh=lane; hh<HH; hh+=64){
    float xv = x[(size_t)t*HH + hh];
#pragma unroll
    for (int e=0;e<EE;e++) acc[e] += xv*gw[hh*EE+e];
  }
#pragma unroll
  for (int e=0;e<EE;e++){
#pragma unroll
    for (int off=1; off<64; off<<=1) acc[e] += __shfl_xor(acc[e], off);
  }
  if (lane==0){
    float m = acc[0];
    for (int e=1;e<EE;e++) m = fmaxf(m, acc[e]);
    float p[EE], s=0.f;
    for (int e=0;e<EE;e++){ p[e]=expf(acc[e]-m); s+=p[e]; }
    float invs = 1.f/s;
    for (int e=0;e<EE;e++) p[e]*=invs;
    int i1=0;
    for (int e=1;e<EE;e++) if (p[e]>p[i1]) i1=e;
    int i2 = (i1==0)?1:0;
    for (int e=0;e<EE;e++) if (e!=i1 && p[e]>p[i2]) i2=e;
    int pos = atomicAdd(&counts[i1],1);
    lists[i1*TT+pos]=t; cw[i1*TT+pos]=p[i1];
    pos = atomicAdd(&counts[i2],1);
    lists[i2*TT+pos]=t; cw[i2*TT+pos]=p[i2];
  }
}

// prefix over experts + slot-indexed gate weights; bases[EE] = total
__global__ void prefix_kernel(const int* __restrict__ c, int* __restrict__ b,
                              const float* __restrict__ cw, float* __restrict__ cw_slot){
  int lane = threadIdx.x;
  __shared__ int sb[EE+1];
  if (lane==0){
    int s=0;
    for (int e=0;e<EE;e++){ sb[e]=s; b[e]=s; s+=c[e]; }
    sb[EE]=s; b[EE]=s;
  }
  __syncthreads();
  for (int e=0;e<EE;e++){
    int cnt=c[e], base=sb[e];
    for (int i=lane;i<cnt;i+=64) cw_slot[base+i]=cw[e*TT+i];
  }
}

// ehb = bf16( gelu(tmp0) * tmp1 * cw_slot[row] )
__global__ void moe_combine(const unsigned short* __restrict__ t0,
                            const unsigned short* __restrict__ t1,
                            const float* __restrict__ cwslot,
                            const int* __restrict__ ntotp,
                            unsigned short* __restrict__ ehb){
  int row = blockIdx.x;
  if (row >= *ntotp) return;
  float c = cwslot[row];
  size_t base = (size_t)row*II;
  int tid = threadIdx.x;
  for (int c0 = tid*8; c0 < II; c0 += 256*8){
    ushort4 x0 = *reinterpret_cast<const ushort4*>(t0+base+c0);
    ushort4 x1 = *reinterpret_cast<const ushort4*>(t0+base+c0+4);
    ushort4 y0 = *reinterpret_cast<const ushort4*>(t1+base+c0);
    ushort4 y1 = *reinterpret_cast<const ushort4*>(t1+base+c0+4);
    ushort4 o0, o1;
    o0.x = f2bf(gelu_tanh(bfval(x0.x))*bfval(y0.x)*c);
    o0.y = f2bf(gelu_tanh(bfval(x0.y))*bfval(y0.y)*c);
    o0.z = f2bf(gelu_tanh(bfval(x0.z))*bfval(y0.z)*c);
    o0.w = f2bf(gelu_tanh(bfval(x0.w))*bfval(y0.w)*c);
    o1.x = f2bf(gelu_tanh(bfval(x1.x))*bfval(y1.x)*c);
    o1.y = f2bf(gelu_tanh(bfval(x1.y))*bfval(y1.y)*c);
    o1.z = f2bf(gelu_tanh(bfval(x1.z))*bfval(y1.z)*c);
    o1.w = f2bf(gelu_tanh(bfval(x1.w))*bfval(y1.w)*c);
    *reinterpret_cast<ushort4*>(ehb+base+c0)   = o0;
    *reinterpret_cast<ushort4*>(ehb+base+c0+4) = o1;
  }
}

// ---------------- transpose + fp32->bf16 (single plane) ----------------
__global__ __launch_bounds__(256) void transpose_cvt(const float* __restrict__ in,
    unsigned short* __restrict__ out, int K, int N){
  __shared__ float tile[64][65];
  int k0 = blockIdx.x*64, n0 = blockIdx.y*64;
  int t = threadIdx.x;
  int c4 = (t&15)*4, g = t>>4;
#pragma unroll
  for (int r=0;r<4;r++){
    int kk = g + r*16;
    float4 v = *reinterpret_cast<const float4*>(in + (size_t)(k0+kk)*N + n0 + c4);
    tile[kk][c4]=v.x; tile[kk][c4+1]=v.y; tile[kk][c4+2]=v.z; tile[kk][c4+3]=v.w;
  }
  __syncthreads();
#pragma unroll
  for (int r=0;r<4;r++){
    int nn = g + r*16;
    ushort4 o;
    o.x=f2bf(tile[c4][nn]);   o.y=f2bf(tile[c4+1][nn]);
    o.z=f2bf(tile[c4+2][nn]); o.w=f2bf(tile[c4+3][nn]);
    *reinterpret_cast<ushort4*>(out + (size_t)(n0+nn)*K + k0 + c4) = o;
  }
}

// ---------------- transpose + split hi/lo ----------------
__global__ __launch_bounds__(256) void transpose_cvt_split(const float* __restrict__ in,
    unsigned short* __restrict__ oh, unsigned short* __restrict__ ol, int K, int N){
  __shared__ float tile[64][65];
  int k0 = blockIdx.x*64, n0 = blockIdx.y*64;
  int t = threadIdx.x;
  int c4 = (t&15)*4, g = t>>4;
#pragma unroll
  for (int r=0;r<4;r++){
    int kk = g + r*16;
    float4 v = *reinterpret_cast<const float4*>(in + (size_t)(k0+kk)*N + n0 + c4);
    tile[kk][c4]=v.x; tile[kk][c4+1]=v.y; tile[kk][c4+2]=v.z; tile[kk][c4+3]=v.w;
  }
  __syncthreads();
#pragma unroll
  for (int r=0;r<4;r++){
    int nn = g + r*16;
    ushort4 h4, l4v;
    split2(tile[c4  ][nn], h4.x, l4v.x);
    split2(tile[c4+1][nn], h4.y, l4v.y);
    split2(tile[c4+2][nn], h4.z, l4v.z);
    split2(tile[c4+3][nn], h4.w, l4v.w);
    size_t o = (size_t)(n0+nn)*K + k0 + c4;
    *reinterpret_cast<ushort4*>(oh + o) = h4;
    *reinterpret_cast<ushort4*>(ol + o) = l4v;
  }
}

// ---------------- split-bf16 3-term MFMA GEMM, double-buffered pipeline ----------------
__global__ __launch_bounds__(256,2) void mgemm_split(
    const unsigned short* __restrict__ Ah, const unsigned short* __restrict__ Alo,
    const unsigned short* __restrict__ Bh, const unsigned short* __restrict__ Blo,
    float* __restrict__ Cf, int N, int K)
{
  int row0 = blockIdx.x*128, col0 = blockIdx.y*128;
  __shared__ __align__(16) unsigned short lds[32768];   // 2 bufs x 4 planes x 4096

  int t = threadIdx.x;
  int lane = t&63, w = t>>6, wr = w>>1, wc = w&1;
  int sr = t>>2, seg = t&3;

  f32x4 acc[4][4];
#pragma unroll
  for (int m=0;m<4;m++)
#pragma unroll
    for (int n=0;n<4;n++) acc[m][n]=f32x4{0,0,0,0};

  int l15 = lane&15, l4 = lane>>4;

  auto stage = [&](int buf, int k0){
    unsigned short* Lb = lds + buf*16384;
#pragma unroll
    for (int i=0;i<2;i++){
      int ldso = (sr + i*64)*32 + seg*8;
      size_t ar = (size_t)(row0 + sr + i*64);
      size_t br = (size_t)(col0 + sr + i*64);
      gl_lds16(Ah  + ar*K + k0 + seg*8, Lb +         ldso);
      gl_lds16(Alo + ar*K + k0 + seg*8, Lb + 4096  + ldso);
      gl_lds16(Bh  + br*K + k0 + seg*8, Lb + 8192  + ldso);
      gl_lds16(Blo + br*K + k0 + seg*8, Lb + 12288 + ldso);
    }
  };

  stage(0, 0);
  __syncthreads();
  int cur = 0;
  int NIT = K/32;
  for (int it=0; it<NIT; it++){
    if (it+1 < NIT) stage(cur^1, (it+1)*32);
    const unsigned short* Lb = lds + cur*16384;
    const bf16x8* Aph = reinterpret_cast<const bf16x8*>(Lb +         (wr*64 + l15)*32 + l4*8);
    const bf16x8* Apl = reinterpret_cast<const bf16x8*>(Lb + 4096  + (wr*64 + l15)*32 + l4*8);
    const bf16x8* Bph = reinterpret_cast<const bf16x8*>(Lb + 8192  + (wc*64 + l15)*32 + l4*8);
    const bf16x8* Bpl = reinterpret_cast<const bf16x8*>(Lb + 12288 + (wc*64 + l15)*32 + l4*8);
    bf16x8 ah[4], al[4], bh[4], bl[4];
#pragma unroll
    for (int m=0;m<4;m++){ ah[m]=Aph[m*64]; al[m]=Apl[m*64]; }
#pragma unroll
    for (int n=0;n<4;n++){ bh[n]=Bph[n*64]; bl[n]=Bpl[n*64]; }
#pragma unroll
    for (int m=0;m<4;m++)
#pragma unroll
      for (int n=0;n<4;n++){
        acc[m][n] = __builtin_amdgcn_mfma_f32_16x16x32_bf16(ah[m], bh[n], acc[m][n], 0,0,0);
        acc[m][n] = __builtin_amdgcn_mfma_f32_16x16x32_bf16(ah[m], bl[n], acc[m][n], 0,0,0);
        acc[m][n] = __builtin_amdgcn_mfma_f32_16x16x32_bf16(al[m], bh[n], acc[m][n], 0,0,0);
      }
    __syncthreads();
    cur ^= 1;
  }

#pragma unroll
  for (int m=0;m<4;m++){
    int rb = wr*64 + m*16 + l4*4;
#pragma unroll
    for (int n=0;n<4;n++){
      int col = col0 + wc*64 + n*16 + l15;
#pragma unroll
      for (int r=0;r<4;r++){
        int row = row0 + rb + r;
        Cf[(size_t)row*N + col] = acc[m][n][r];
      }
    }
  }
}

// ---------------- bf16 MFMA GEMM (MoE expert path) ----------------
// BK=32, 3-buffer depth-2 pipeline with counted vmcnt + raw s_barrier.
// XCD-aware 1-D grid: bid = x*8 + (g%8) + (g/8)*128, g = y + NY*e. All row-blocks
// (x) sharing a B col-tile (same y,e) have bid ≡ g (mod 8) -> same XCD -> B tile
// fetched into one L2 instead of 8.
// MODE 1 (up): NY=64; y: parity selects w_in/w_v plane, y>>1 = col tile. grid 16*64*EE.
// MODE 2 (down): NY=16; y&7 = col tile, y>>3 = K-section (x2). grid 16*16*EE.
template<int MODE>
__global__ __launch_bounds__(256,3) void mgemm(
    const unsigned short* __restrict__ A, const unsigned short* __restrict__ B0b,
    const unsigned short* __restrict__ B1b, size_t bstride,
    float* __restrict__ Cf, unsigned short* __restrict__ Cb0, unsigned short* __restrict__ Cb1,
    int N, int K,
    const int* __restrict__ listb,
    const int* __restrict__ countb, const int* __restrict__ basep)
{
  int bid = blockIdx.x;
  int qq = bid >> 7, rr = bid & 127;
  int xti = rr >> 3, sbit = rr & 7;
  int g = qq*8 + sbit;
  int y, e;
  if (MODE==1){ y = g & 63; e = g >> 6; }
  else        { y = g & 15; e = g >> 4; }

  int M = countb[e];
  int row0 = xti*128;
  if (row0 >= M) return;
  int which = 0, col0, kbase = 0, KL = K;
  const unsigned short* B;
  if (MODE==1){
    which = y & 1;
    col0 = (y >> 1)*128;
    B = (which ? B1b : B0b) + bstride*e;
  } else {
    col0 = (y & 7)*128;
    kbase = (y >> 3)*(K/2);
    KL = K/2;
    B = B0b + bstride*e;
  }
  int slot = basep ? basep[e] : 0;
  const int* rowlist = listb + e*TT;

  // 3 bufs x (A[128][32] + B[128][32]) bf16 = 48 KB -> 3 blocks/CU
  __shared__ __align__(16) unsigned short lds[3][2][4096];

  int t = threadIdx.x;
  int lane = t&63, w = t>>6, wr = w>>1, wc = w&1;
  int sr = t>>2, seg = t&3;

  size_t arow[2], brow[2];
#pragma unroll
  for (int i=0;i<2;i++){
    int r = row0 + sr + i*64;
    int rc = (r < M) ? r : (M-1);
    if (MODE==1) arow[i] = (size_t)rowlist[rc];
    else         arow[i] = (size_t)(slot + rc);
    brow[i] = (size_t)(col0 + sr + i*64);
  }

  f32x4 acc[4][4];
#pragma unroll
  for (int m=0;m<4;m++)
#pragma unroll
    for (int n=0;n<4;n++) acc[m][n]=f32x4{0,0,0,0};

  int l15 = lane&15, l4 = lane>>4;

  auto stage = [&](int buf, int k0){
#pragma unroll
    for (int i=0;i<2;i++){
      int ldso = (sr + i*64)*32 + seg*8;
      gl_lds16(A + arow[i]*K + kbase + k0 + seg*8, &lds[buf][0][0] + ldso);
      gl_lds16(B + brow[i]*K + kbase + k0 + seg*8, &lds[buf][1][0] + ldso);
    }
  };

  int NIT = KL/32;
  stage(0, 0);
  if (NIT > 1) stage(1, 32);

  for (int it=0; it<NIT; it++){
    if (it+1 < NIT) asm volatile("s_waitcnt vmcnt(4)" ::: "memory");
    else            asm volatile("s_waitcnt vmcnt(0)" ::: "memory");
    __builtin_amdgcn_s_barrier();
    if (it+2 < NIT) stage((it+2)%3, (it+2)*32);

    int cb = it%3;
    const unsigned short* La = &lds[cb][0][0];
    const unsigned short* Lb = &lds[cb][1][0];
    bf16x8 af[4], bf[4];
#pragma unroll
    for (int m=0;m<4;m++)
      af[m] = *reinterpret_cast<const bf16x8*>(La + (wr*64 + m*16 + l15)*32 + l4*8);
#pragma unroll
    for (int n=0;n<4;n++)
      bf[n] = *reinterpret_cast<const bf16x8*>(Lb + (wc*64 + n*16 + l15)*32 + l4*8);
#pragma unroll
    for (int m=0;m<4;m++)
#pragma unroll
      for (int n=0;n<4;n++)
        acc[m][n] = __builtin_amdgcn_mfma_f32_16x16x32_bf16(af[m], bf[n], acc[m][n], 0,0,0);
  }

  unsigned short* Cb = which ? Cb1 : Cb0;
#pragma unroll
  for (int m=0;m<4;m++){
    int rb = wr*64 + m*16 + l4*4;
#pragma unroll
    for (int n=0;n<4;n++){
      int col = col0 + wc*64 + n*16 + l15;
#pragma unroll
      for (int r=0;r<4;r++){
        int row = row0 + rb + r;
        if (row >= M) continue;
        float v = acc[m][n][r];
        if (MODE==1){
          Cb[(size_t)(slot+row)*N + col] = f2bf(v);
        } else {
          atomicAdd(&Cf[(size_t)rowlist[row]*N + col], v);
        }
      }
    }
  }
}

} // namespace

extern "C" void kernel_launch(void* const* d_in, const int* in_sizes, int n_in,
                              void* d_out, int out_size, void* d_ws, size_t ws_size,
                              hipStream_t stream) {
  const float* hidden = (const float*)d_in[0];
  const int*   mask   = (const int*)d_in[1];
  const int*   pos    = (const int*)d_in[2];
  const float* q_w    = (const float*)d_in[3];
  const float* k_w    = (const float*)d_in[4];
  const float* v_w    = (const float*)d_in[5];
  const float* o_w    = (const float*)d_in[6];
  const float* pre_attn_scale  = (const float*)d_in[7];
  const float* post_attn_scale = (const float*)d_in[8];
  const float* pre_moe_scale   = (const float*)d_in[9];
  const float* post_moe_scale  = (const float*)d_in[10];
  const float* gate_w = (const float*)d_in[11];
  const float* w_in   = (const float*)d_in[12];
  const float* w_v    = (const float*)d_in[13];
  const float* w_out  = (const float*)d_in[14];
  float* out = (float*)d_out;

  char* base = (char*)d_ws;
  auto carve = [&](size_t bytes)->char*{
    char* r = base; base += (bytes + 255) & ~(size_t)255; return r;
  };
  float* hn  = (float*)carve((size_t)TT*HH*4);
  unsigned short* hnb = (unsigned short*)carve((size_t)TT*HH*2);
  unsigned short* hnh = (unsigned short*)carve((size_t)TT*HH*2);
  unsigned short* hnl = (unsigned short*)carve((size_t)TT*HH*2);
  float* qkvb = (float*)carve((size_t)TT*QKV*4);
  unsigned short* qsh = (unsigned short*)carve((size_t)TT*NH*DH*2);
  unsigned short* qsl = (unsigned short*)carve((size_t)TT*NH*DH*2);
  unsigned short* ksh = (unsigned short*)carve((size_t)TT*NKV*DH*2);
  unsigned short* ksl = (unsigned short*)carve((size_t)TT*NKV*DH*2);
  unsigned short* vth = (unsigned short*)carve((size_t)TT*NKV*DH*2);
  unsigned short* vtl = (unsigned short*)carve((size_t)TT*NKV*DH*2);
  unsigned short* ctxh = (unsigned short*)carve((size_t)TT*NH*DH*2);
  unsigned short* ctxl = (unsigned short*)carve((size_t)TT*NH*DH*2);
  float* ao  = (float*)carve((size_t)TT*HH*4);
  float* xb  = (float*)carve((size_t)TT*HH*4);
  float* moe = (float*)carve((size_t)TT*HH*4);
  float* cw  = (float*)carve((size_t)EE*TT*4);
  float* cw_slot = (float*)carve((size_t)2*TT*4);
  int* counts = (int*)carve(64*4);
  int* bases  = (int*)carve(64*4);
  int* lists  = (int*)carve((size_t)EE*TT*4);
  unsigned short* qkvwTh = (unsigned short*)carve((size_t)QKV*HH*2);
  unsigned short* qkvwTl = (unsigned short*)carve((size_t)QKV*HH*2);
  unsigned short* owTh = (unsigned short*)carve((size_t)NH*DH*HH*2);
  unsigned short* owTl = (unsigned short*)carve((size_t)NH*DH*HH*2);
  unsigned short* ehb   = (unsigned short*)carve((size_t)2*TT*II*2);
  unsigned short* tmp0  = (unsigned short*)carve((size_t)2*TT*II*2);
  unsigned short* tmp1  = (unsigned short*)carve((size_t)2*TT*II*2);
  unsigned short* winT  = (unsigned short*)carve((size_t)EE*II*HH*2);
  unsigned short* wvT   = (unsigned short*)carve((size_t)EE*II*HH*2);
  unsigned short* woutT = (unsigned short*)carve((size_t)EE*HH*II*2);
  size_t estride = (size_t)II*HH;

  // ---- attention block (split-bf16, fp32-accurate) ----
  rmsnorm_kernel<<<TT,256,0,stream>>>(hidden, pre_attn_scale, nullptr, nullptr, hnh, hnl);
  transpose_cvt_split<<<dim3(16,16),256,0,stream>>>(q_w, qkvwTh, qkvwTl, HH, NH*DH);
  transpose_cvt_split<<<dim3(16,4), 256,0,stream>>>(k_w, qkvwTh + (size_t)1024*HH, qkvwTl + (size_t)1024*HH, HH, NKV*DH);
  transpose_cvt_split<<<dim3(16,4), 256,0,stream>>>(v_w, qkvwTh + (size_t)1280*HH, qkvwTl + (size_t)1280*HH, HH, NKV*DH);
  transpose_cvt_split<<<dim3(16,16),256,0,stream>>>(o_w, owTh, owTl, NH*DH, HH);

  mgemm_split<<<dim3(16,QKV/128),256,0,stream>>>(hnh, hnl, qkvwTh, qkvwTl, qkvb, QKV, HH);

  rope_split_kernel<<<(TT*NH*32+255)/256,256,0,stream>>>(qkvb, QKV, 0, pos, qsh, qsl, NH);
  rope_split_kernel<<<(TT*NKV*32+255)/256,256,0,stream>>>(qkvb, QKV, 1024, pos, ksh, ksl, NKV);
  vt_split_kernel<<<dim3(SS/64,NKV,BB),256,0,stream>>>(qkvb, QKV, 1280, vth, vtl);

  attn_mfma<<<dim3(SS/64,NH,BB),256,0,stream>>>(qsh, qsl, ksh, ksl, vth, vtl, mask, ctxh, ctxl);

  mgemm_split<<<dim3(16,HH/128),256,0,stream>>>(ctxh, ctxl, owTh, owTl, ao, HH, NH*DH);
  rmsnorm_kernel<<<TT,256,0,stream>>>(ao, post_attn_scale, ao, nullptr, nullptr, nullptr);
  add_kernel<<<(TT*HH)/256,256,0,stream>>>(hidden, ao, xb, TT*HH);

  // ---- MoE block (routing fp32, experts bf16) ----
  rmsnorm_kernel<<<TT,256,0,stream>>>(xb, pre_moe_scale, hn, hnb, nullptr, nullptr);
  hipMemsetAsync(counts, 0, 64*sizeof(int), stream);
  hipMemsetAsync(moe, 0, (size_t)TT*HH*sizeof(float), stream);
  route_kernel<<<TT,64,0,stream>>>(hn, gate_w, counts, lists, cw);
  prefix_kernel<<<1,64,0,stream>>>(counts, bases, cw, cw_slot);

  for (int e=0;e<EE;e++){
    transpose_cvt<<<dim3(16,64),256,0,stream>>>(w_in + (size_t)e*HH*II, winT + (size_t)e*estride, HH, II);
    transpose_cvt<<<dim3(16,64),256,0,stream>>>(w_v  + (size_t)e*HH*II, wvT  + (size_t)e*estride, HH, II);
    transpose_cvt<<<dim3(64,16),256,0,stream>>>(w_out+ (size_t)e*II*HH, woutT+ (size_t)e*estride, II, HH);
  }

  // up: XCD-remapped 1-D grid, 16 row-tiles x 64 (plane|col) x 8 experts
  mgemm<1><<<16*64*EE,256,0,stream>>>(hnb, winT, wvT, estride, nullptr, tmp0, tmp1,
      II, HH, lists, counts, bases);
  moe_combine<<<2*TT,256,0,stream>>>(tmp0, tmp1, cw_slot, bases+EE, ehb);
  // down: XCD-remapped 1-D grid, 16 row-tiles x 16 (col|ksec) x 8 experts, K-split x2
  mgemm<2><<<16*16*EE,256,0,stream>>>(ehb, woutT, nullptr, estride, moe, nullptr, nullptr,
      HH, II, lists, counts, bases);

  rmsnorm_kernel<<<TT,256,0,stream>>>(moe, post_moe_scale, moe, nullptr, nullptr, nullptr);
  add_kernel<<<(TT*HH)/256,256,0,stream>>>(xb, moe, out, TT*HH);
}

// Round 13
// 633.126 us; speedup vs baseline: 1.6871x; 1.0725x over previous
//
#include <hip/hip_runtime.h>
#include <hip/hip_bf16.h>
#include <math.h>

namespace {

constexpr int BB=2, SS=1024, HH=1024, NH=16, NKV=4, DH=64;
constexpr int II=4096, EE=8;
constexpr int TT=BB*SS;
constexpr int QKV=1536;                 // merged projection width: 1024 q + 256 k + 256 v
constexpr float EPS=1e-5f;

typedef __bf16 bf16x8 __attribute__((ext_vector_type(8)));
typedef float f32x4 __attribute__((ext_vector_type(4)));

__device__ __forceinline__ unsigned short f2bf(float x){
  union { float f; unsigned u; } un; un.f = x;
  unsigned r = un.u + 0x7fffu + ((un.u>>16)&1u);
  return (unsigned short)(r>>16);
}
__device__ __forceinline__ float bfval(unsigned short h){
  union { unsigned u; float f; } r; r.u = ((unsigned)h)<<16; return r.f;
}
__device__ __forceinline__ void split2(float v, unsigned short& hi, unsigned short& lo){
  hi = f2bf(v);
  lo = f2bf(v - bfval(hi));
}

__device__ __forceinline__ void gl_lds16(const void* g, void* l){
  __builtin_amdgcn_global_load_lds(
    (const __attribute__((address_space(1))) unsigned int*)g,
    (__attribute__((address_space(3))) unsigned int*)l, 16, 0, 0);
}

__device__ __forceinline__ float gelu_tanh(float x){
  float x3 = x*x*x;
  return 0.5f*x*(1.f + tanhf(0.7978845608028654f*(x + 0.044715f*x3)));
}

// ---------------- RMSNorm: optional fp32 / bf16 / split outputs ----------------
__global__ void rmsnorm_kernel(const float* __restrict__ in, const float* __restrict__ scale,
                               float* __restrict__ outf, unsigned short* __restrict__ outb,
                               unsigned short* __restrict__ outh, unsigned short* __restrict__ outl){
  int row = blockIdx.x, tid = threadIdx.x;
  const float* x = in + (size_t)row*HH;
  float ss = 0.f;
  for (int i=tid;i<HH;i+=256){ float v=x[i]; ss+=v*v; }
  __shared__ float red[256];
  red[tid]=ss; __syncthreads();
  for (int s=128;s>0;s>>=1){ if(tid<s) red[tid]+=red[tid+s]; __syncthreads(); }
  float inv = rsqrtf(red[0]/(float)HH + EPS);
  for (int i=tid;i<HH;i+=256){
    float v = x[i]*inv*scale[i];
    size_t o = (size_t)row*HH+i;
    if (outf) outf[o]=v;
    if (outb) outb[o]=f2bf(v);
    if (outh){ unsigned short h,l; split2(v,h,l); outh[o]=h; outl[o]=l; }
  }
}

__global__ void add_kernel(const float* __restrict__ a, const float* __restrict__ b,
                           float* __restrict__ o, int n){
  int i = blockIdx.x*256 + threadIdx.x;
  if (i < n) o[i] = a[i] + b[i];
}

// ---------------- RoPE from merged proj buffer -> split bf16 planes ----------------
__global__ void rope_split_kernel(const float* __restrict__ x, int stride, int off,
                                  const int* __restrict__ pos_ids,
                                  unsigned short* __restrict__ oh, unsigned short* __restrict__ ol,
                                  int nheads){
  int idx = blockIdx.x*256 + threadIdx.x;
  int total = TT*nheads*32;
  if (idx >= total) return;
  int j = idx & 31;
  int hh = (idx>>5) % nheads;
  int t = idx / (32*nheads);
  float pos = (float)pos_ids[t];
  float inv_freq = powf(10000.f, -(float)j/32.f);
  float ang = pos * inv_freq;
  float s, c; sincosf(ang, &s, &c);
  const float* p = x + (size_t)t*stride + off + hh*DH;
  float x1 = p[j], x2 = p[j+32];
  float r1 = x1*c - x2*s;
  float r2 = x2*c + x1*s;
  size_t o = ((size_t)t*nheads + hh)*DH;
  unsigned short h1,l1,h2,l2;
  split2(r1,h1,l1); split2(r2,h2,l2);
  oh[o+j]=h1;    ol[o+j]=l1;
  oh[o+j+32]=h2; ol[o+j+32]=l2;
}

// ---------------- V transpose (from merged proj) -> split bf16 Vt[b][kvh][d][S] ----------------
__global__ __launch_bounds__(256) void vt_split_kernel(const float* __restrict__ src, int stride, int off,
    unsigned short* __restrict__ vth, unsigned short* __restrict__ vtl){
  int k0 = blockIdx.x*64;
  int kvh = blockIdx.y;
  int b = blockIdx.z;
  __shared__ float tile[64][65];
  int t = threadIdx.x;
  int c4 = (t&15)*4, gg = t>>4;
#pragma unroll
  for (int r=0;r<4;r++){
    int kk = gg + r*16;
    float4 v = *reinterpret_cast<const float4*>(src + (size_t)(b*SS+k0+kk)*stride + off + kvh*DH + c4);
    tile[kk][c4]=v.x; tile[kk][c4+1]=v.y; tile[kk][c4+2]=v.z; tile[kk][c4+3]=v.w;
  }
  __syncthreads();
#pragma unroll
  for (int r=0;r<4;r++){
    int dd = gg + r*16;
    ushort4 h4, l4v;
    split2(tile[c4  ][dd], h4.x, l4v.x);
    split2(tile[c4+1][dd], h4.y, l4v.y);
    split2(tile[c4+2][dd], h4.z, l4v.z);
    split2(tile[c4+3][dd], h4.w, l4v.w);
    size_t o = ((size_t)(b*NKV+kvh)*DH + dd)*SS + k0 + c4;
    *reinterpret_cast<ushort4*>(vth+o)=h4;
    *reinterpret_cast<ushort4*>(vtl+o)=l4v;
  }
}

// ---------------- MFMA flash attention (split-bf16, fp32-accurate) ----------------
__global__ __launch_bounds__(256) void attn_mfma(
    const unsigned short* __restrict__ qh, const unsigned short* __restrict__ ql,
    const unsigned short* __restrict__ khp, const unsigned short* __restrict__ klp,
    const unsigned short* __restrict__ vth, const unsigned short* __restrict__ vtl,
    const int* __restrict__ amask,
    unsigned short* __restrict__ ctxh, unsigned short* __restrict__ ctxl)
{
  int qb = blockIdx.x, h = blockIdx.y, b = blockIdx.z;
  int kvh = h >> 2;
  int tid = threadIdx.x;
  int w = tid >> 6, lane = tid & 63;
  int g = lane >> 4, l15 = lane & 15;

  __shared__ __align__(16) unsigned short Klh[64*64];
  __shared__ __align__(16) unsigned short Kll[64*64];
  __shared__ __align__(16) unsigned short Vlh[64*64];
  __shared__ __align__(16) unsigned short Vll[64*64];
  __shared__ __align__(16) unsigned short Pst[4][2][16*72];

  int q0w = qb*64 + w*16;

  bf16x8 qfh[2], qfl[2];
  {
    size_t qrow = ((size_t)(b*SS + q0w + l15)*NH + h)*DH;
#pragma unroll
    for (int ks=0; ks<2; ks++){
      qfh[ks] = *reinterpret_cast<const bf16x8*>(qh + qrow + ks*32 + g*8);
      qfl[ks] = *reinterpret_cast<const bf16x8*>(ql + qrow + ks*32 + g*8);
    }
  }

  f32x4 acc[4];
  float m_run[4], l_run[4];
#pragma unroll
  for (int i=0;i<4;i++){ acc[i]=f32x4{0,0,0,0}; m_run[i]=-1e30f; l_run[i]=0.f; }

  int nkv = qb + 1;
  for (int kblk=0; kblk<nkv; kblk++){
    int k0 = kblk*64;
    __syncthreads();
#pragma unroll
    for (int shot=0; shot<2; shot++){
      int a = shot*256 + tid;
      int row = a>>3, seg = a&7;
      int ss8 = (seg ^ (row&7))*8;
      int lo = row*64 + seg*8;
      size_t kg = ((size_t)(b*SS + k0 + row)*NKV + kvh)*DH + ss8;
      size_t vg = ((size_t)(b*NKV + kvh)*DH + row)*SS + k0 + ss8;
      gl_lds16(khp + kg, Klh + lo);
      gl_lds16(klp + kg, Kll + lo);
      gl_lds16(vth + vg, Vlh + lo);
      gl_lds16(vtl + vg, Vll + lo);
    }
    __syncthreads();

    f32x4 sf[4];
#pragma unroll
    for (int nf=0;nf<4;nf++) sf[nf]=f32x4{0,0,0,0};
#pragma unroll
    for (int ks=0; ks<2; ks++){
#pragma unroll
      for (int nf=0; nf<4; nf++){
        int krow = nf*16 + l15;
        int off = krow*64 + (((ks*4+g) ^ (krow&7))*8);
        bf16x8 bh = *reinterpret_cast<const bf16x8*>(Klh + off);
        bf16x8 bl = *reinterpret_cast<const bf16x8*>(Kll + off);
        sf[nf] = __builtin_amdgcn_mfma_f32_16x16x32_bf16(qfh[ks], bh, sf[nf],0,0,0);
        sf[nf] = __builtin_amdgcn_mfma_f32_16x16x32_bf16(qfh[ks], bl, sf[nf],0,0,0);
        sf[nf] = __builtin_amdgcn_mfma_f32_16x16x32_bf16(qfl[ks], bh, sf[nf],0,0,0);
      }
    }

    int am4[4];
#pragma unroll
    for (int nf=0;nf<4;nf++) am4[nf] = amask[b*SS + k0 + nf*16 + l15];
#pragma unroll
    for (int nf=0;nf<4;nf++){
      int k_abs = k0 + nf*16 + l15;
#pragma unroll
      for (int r=0;r<4;r++){
        float s = sf[nf][r]*0.125f;
        int q_abs = q0w + g*4 + r;
        if (k_abs > q_abs || am4[nf] <= 0) s = -1e9f;
        sf[nf][r] = s;
      }
    }

    float m_new[4], fsc[4];
#pragma unroll
    for (int r=0;r<4;r++){
      float v = fmaxf(fmaxf(sf[0][r],sf[1][r]), fmaxf(sf[2][r],sf[3][r]));
#pragma unroll
      for (int o=1;o<16;o<<=1) v = fmaxf(v, __shfl_xor(v,o));
      m_new[r] = fmaxf(m_run[r], v);
      fsc[r] = expf(m_run[r] - m_new[r]);
      m_run[r] = m_new[r];
    }

    unsigned short* Ph  = Pst[w][0];
    unsigned short* Plo = Pst[w][1];
    float rsum[4] = {0.f,0.f,0.f,0.f};
#pragma unroll
    for (int nf=0;nf<4;nf++){
#pragma unroll
      for (int r=0;r<4;r++){
        float p = expf(sf[nf][r] - m_new[r]);
        rsum[r] += p;
        unsigned short hi = f2bf(p);
        float lo = p - bfval(hi);
        Ph [(g*4+r)*72 + nf*16 + l15] = hi;
        Plo[(g*4+r)*72 + nf*16 + l15] = f2bf(lo);
      }
    }
#pragma unroll
    for (int r=0;r<4;r++){
#pragma unroll
      for (int o=1;o<16;o<<=1) rsum[r] += __shfl_xor(rsum[r],o);
      l_run[r] = l_run[r]*fsc[r] + rsum[r];
#pragma unroll
      for (int nf=0;nf<4;nf++) acc[nf][r] *= fsc[r];
    }

#pragma unroll
    for (int ks=0; ks<2; ks++){
      bf16x8 pa = *reinterpret_cast<const bf16x8*>(Ph  + l15*72 + ks*32 + g*8);
      bf16x8 pl = *reinterpret_cast<const bf16x8*>(Plo + l15*72 + ks*32 + g*8);
#pragma unroll
      for (int nf=0; nf<4; nf++){
        int drow = nf*16 + l15;
        int off = drow*64 + (((ks*4+g) ^ (drow&7))*8);
        bf16x8 vh = *reinterpret_cast<const bf16x8*>(Vlh + off);
        bf16x8 vl = *reinterpret_cast<const bf16x8*>(Vll + off);
        acc[nf] = __builtin_amdgcn_mfma_f32_16x16x32_bf16(pa, vh, acc[nf],0,0,0);
        acc[nf] = __builtin_amdgcn_mfma_f32_16x16x32_bf16(pa, vl, acc[nf],0,0,0);
        acc[nf] = __builtin_amdgcn_mfma_f32_16x16x32_bf16(pl, vh, acc[nf],0,0,0);
      }
    }
  }

#pragma unroll
  for (int r=0;r<4;r++){
    float inv = 1.f / l_run[r];
    size_t orow = ((size_t)(b*SS + q0w + g*4 + r)*NH + h)*DH;
#pragma unroll
    for (int nf=0;nf<4;nf++){
      float v = acc[nf][r]*inv;
      unsigned short hi,lo; split2(v,hi,lo);
      ctxh[orow + nf*16 + l15] = hi;
      ctxl[orow + nf*16 + l15] = lo;
    }
  }
}

// ---------------- MoE routing ----------------
__global__ void route_kernel(const float* __restrict__ x, const float* __restrict__ gw,
                             int* __restrict__ counts, int* __restrict__ lists,
                             float* __restrict__ cw){
  int t = blockIdx.x;
  int lane = threadIdx.x;
  float acc[EE];
#pragma unroll
  for (int e=0;e<EE;e++) acc[e]=0.f;
  for (int hh=lane; hh<HH; hh+=64){
    float xv = x[(size_t)t*HH + hh];
#pragma unroll
    for (int e=0;e<EE;e++) acc[e] += xv*gw[hh*EE+e];
  }
#pragma unroll
  for (int e=0;e<EE;e++){
#pragma unroll
    for (int off=1; off<64; off<<=1) acc[e] += __shfl_xor(acc[e], off);
  }
  if (lane==0){
    float m = acc[0];
    for (int e=1;e<EE;e++) m = fmaxf(m, acc[e]);
    float p[EE], s=0.f;
    for (int e=0;e<EE;e++){ p[e]=expf(acc[e]-m); s+=p[e]; }
    float invs = 1.f/s;
    for (int e=0;e<EE;e++) p[e]*=invs;
    int i1=0;
    for (int e=1;e<EE;e++) if (p[e]>p[i1]) i1=e;
    int i2 = (i1==0)?1:0;
    for (int e=0;e<EE;e++) if (e!=i1 && p[e]>p[i2]) i2=e;
    int pos = atomicAdd(&counts[i1],1);
    lists[i1*TT+pos]=t; cw[i1*TT+pos]=p[i1];
    pos = atomicAdd(&counts[i2],1);
    lists[i2*TT+pos]=t; cw[i2*TT+pos]=p[i2];
  }
}

// prefix over experts + slot-indexed gate weights; bases[EE] = total
__global__ void prefix_kernel(const int* __restrict__ c, int* __restrict__ b,
                              const float* __restrict__ cw, float* __restrict__ cw_slot){
  int lane = threadIdx.x;
  __shared__ int sb[EE+1];
  if (lane==0){
    int s=0;
    for (int e=0;e<EE;e++){ sb[e]=s; b[e]=s; s+=c[e]; }
    sb[EE]=s; b[EE]=s;
  }
  __syncthreads();
  for (int e=0;e<EE;e++){
    int cnt=c[e], base=sb[e];
    for (int i=lane;i<cnt;i+=64) cw_slot[base+i]=cw[e*TT+i];
  }
}

// ehb = bf16( gelu(tmp0) * tmp1 * cw_slot[row] )
__global__ void moe_combine(const unsigned short* __restrict__ t0,
                            const unsigned short* __restrict__ t1,
                            const float* __restrict__ cwslot,
                            const int* __restrict__ ntotp,
                            unsigned short* __restrict__ ehb){
  int row = blockIdx.x;
  if (row >= *ntotp) return;
  float c = cwslot[row];
  size_t base = (size_t)row*II;
  int tid = threadIdx.x;
  for (int c0 = tid*8; c0 < II; c0 += 256*8){
    ushort4 x0 = *reinterpret_cast<const ushort4*>(t0+base+c0);
    ushort4 x1 = *reinterpret_cast<const ushort4*>(t0+base+c0+4);
    ushort4 y0 = *reinterpret_cast<const ushort4*>(t1+base+c0);
    ushort4 y1 = *reinterpret_cast<const ushort4*>(t1+base+c0+4);
    ushort4 o0, o1;
    o0.x = f2bf(gelu_tanh(bfval(x0.x))*bfval(y0.x)*c);
    o0.y = f2bf(gelu_tanh(bfval(x0.y))*bfval(y0.y)*c);
    o0.z = f2bf(gelu_tanh(bfval(x0.z))*bfval(y0.z)*c);
    o0.w = f2bf(gelu_tanh(bfval(x0.w))*bfval(y0.w)*c);
    o1.x = f2bf(gelu_tanh(bfval(x1.x))*bfval(y1.x)*c);
    o1.y = f2bf(gelu_tanh(bfval(x1.y))*bfval(y1.y)*c);
    o1.z = f2bf(gelu_tanh(bfval(x1.z))*bfval(y1.z)*c);
    o1.w = f2bf(gelu_tanh(bfval(x1.w))*bfval(y1.w)*c);
    *reinterpret_cast<ushort4*>(ehb+base+c0)   = o0;
    *reinterpret_cast<ushort4*>(ehb+base+c0+4) = o1;
  }
}

// ---------------- transpose + fp32->bf16 (single plane), batched over z ----------------
__global__ __launch_bounds__(256) void transpose_cvt(const float* __restrict__ in,
    unsigned short* __restrict__ out, int K, int N, size_t in_zstride, size_t out_zstride){
  __shared__ float tile[64][65];
  int k0 = blockIdx.x*64, n0 = blockIdx.y*64;
  const float* inz = in + in_zstride*blockIdx.z;
  unsigned short* outz = out + out_zstride*blockIdx.z;
  int t = threadIdx.x;
  int c4 = (t&15)*4, g = t>>4;
#pragma unroll
  for (int r=0;r<4;r++){
    int kk = g + r*16;
    float4 v = *reinterpret_cast<const float4*>(inz + (size_t)(k0+kk)*N + n0 + c4);
    tile[kk][c4]=v.x; tile[kk][c4+1]=v.y; tile[kk][c4+2]=v.z; tile[kk][c4+3]=v.w;
  }
  __syncthreads();
#pragma unroll
  for (int r=0;r<4;r++){
    int nn = g + r*16;
    ushort4 o;
    o.x=f2bf(tile[c4][nn]);   o.y=f2bf(tile[c4+1][nn]);
    o.z=f2bf(tile[c4+2][nn]); o.w=f2bf(tile[c4+3][nn]);
    *reinterpret_cast<ushort4*>(outz + (size_t)(n0+nn)*K + k0 + c4) = o;
  }
}

// ---------------- transpose + split hi/lo ----------------
__global__ __launch_bounds__(256) void transpose_cvt_split(const float* __restrict__ in,
    unsigned short* __restrict__ oh, unsigned short* __restrict__ ol, int K, int N){
  __shared__ float tile[64][65];
  int k0 = blockIdx.x*64, n0 = blockIdx.y*64;
  int t = threadIdx.x;
  int c4 = (t&15)*4, g = t>>4;
#pragma unroll
  for (int r=0;r<4;r++){
    int kk = g + r*16;
    float4 v = *reinterpret_cast<const float4*>(in + (size_t)(k0+kk)*N + n0 + c4);
    tile[kk][c4]=v.x; tile[kk][c4+1]=v.y; tile[kk][c4+2]=v.z; tile[kk][c4+3]=v.w;
  }
  __syncthreads();
#pragma unroll
  for (int r=0;r<4;r++){
    int nn = g + r*16;
    ushort4 h4, l4v;
    split2(tile[c4  ][nn], h4.x, l4v.x);
    split2(tile[c4+1][nn], h4.y, l4v.y);
    split2(tile[c4+2][nn], h4.z, l4v.z);
    split2(tile[c4+3][nn], h4.w, l4v.w);
    size_t o = (size_t)(n0+nn)*K + k0 + c4;
    *reinterpret_cast<ushort4*>(oh + o) = h4;
    *reinterpret_cast<ushort4*>(ol + o) = l4v;
  }
}

// ---------------- split-bf16 3-term MFMA GEMM, dbuf, XCD-remapped grid ----------------
// 1-D grid: bid = qq*128 + xti*8 + sbit; g = qq*8+sbit = col tile; guard g<NY.
// All 16 row-tiles of a col tile share bid%8 -> same XCD -> B tile L2-local.
__global__ __launch_bounds__(256,2) void mgemm_split(
    const unsigned short* __restrict__ Ah, const unsigned short* __restrict__ Alo,
    const unsigned short* __restrict__ Bh, const unsigned short* __restrict__ Blo,
    float* __restrict__ Cf, int NY, int N, int K)
{
  int bid = blockIdx.x;
  int qq = bid >> 7, rr = bid & 127;
  int xti = rr >> 3, sbit = rr & 7;
  int g = qq*8 + sbit;
  if (g >= NY) return;
  int row0 = xti*128, col0 = g*128;
  __shared__ __align__(16) unsigned short lds[32768];   // 2 bufs x 4 planes x 4096

  int t = threadIdx.x;
  int lane = t&63, w = t>>6, wr = w>>1, wc = w&1;
  int sr = t>>2, seg = t&3;

  f32x4 acc[4][4];
#pragma unroll
  for (int m=0;m<4;m++)
#pragma unroll
    for (int n=0;n<4;n++) acc[m][n]=f32x4{0,0,0,0};

  int l15 = lane&15, l4 = lane>>4;

  auto stage = [&](int buf, int k0){
    unsigned short* Lb = lds + buf*16384;
#pragma unroll
    for (int i=0;i<2;i++){
      int ldso = (sr + i*64)*32 + seg*8;
      size_t ar = (size_t)(row0 + sr + i*64);
      size_t br = (size_t)(col0 + sr + i*64);
      gl_lds16(Ah  + ar*K + k0 + seg*8, Lb +         ldso);
      gl_lds16(Alo + ar*K + k0 + seg*8, Lb + 4096  + ldso);
      gl_lds16(Bh  + br*K + k0 + seg*8, Lb + 8192  + ldso);
      gl_lds16(Blo + br*K + k0 + seg*8, Lb + 12288 + ldso);
    }
  };

  stage(0, 0);
  __syncthreads();
  int cur = 0;
  int NIT = K/32;
  for (int it=0; it<NIT; it++){
    if (it+1 < NIT) stage(cur^1, (it+1)*32);
    const unsigned short* Lb = lds + cur*16384;
    const bf16x8* Aph = reinterpret_cast<const bf16x8*>(Lb +         (wr*64 + l15)*32 + l4*8);
    const bf16x8* Apl = reinterpret_cast<const bf16x8*>(Lb + 4096  + (wr*64 + l15)*32 + l4*8);
    const bf16x8* Bph = reinterpret_cast<const bf16x8*>(Lb + 8192  + (wc*64 + l15)*32 + l4*8);
    const bf16x8* Bpl = reinterpret_cast<const bf16x8*>(Lb + 12288 + (wc*64 + l15)*32 + l4*8);
    bf16x8 ah[4], al[4], bh[4], bl[4];
#pragma unroll
    for (int m=0;m<4;m++){ ah[m]=Aph[m*64]; al[m]=Apl[m*64]; }
#pragma unroll
    for (int n=0;n<4;n++){ bh[n]=Bph[n*64]; bl[n]=Bpl[n*64]; }
#pragma unroll
    for (int m=0;m<4;m++)
#pragma unroll
      for (int n=0;n<4;n++){
        acc[m][n] = __builtin_amdgcn_mfma_f32_16x16x32_bf16(ah[m], bh[n], acc[m][n], 0,0,0);
        acc[m][n] = __builtin_amdgcn_mfma_f32_16x16x32_bf16(ah[m], bl[n], acc[m][n], 0,0,0);
        acc[m][n] = __builtin_amdgcn_mfma_f32_16x16x32_bf16(al[m], bh[n], acc[m][n], 0,0,0);
      }
    __syncthreads();
    cur ^= 1;
  }

#pragma unroll
  for (int m=0;m<4;m++){
    int rb = wr*64 + m*16 + l4*4;
#pragma unroll
    for (int n=0;n<4;n++){
      int col = col0 + wc*64 + n*16 + l15;
#pragma unroll
      for (int r=0;r<4;r++){
        int row = row0 + rb + r;
        Cf[(size_t)row*N + col] = acc[m][n][r];
      }
    }
  }
}

// ---------------- bf16 MFMA GEMM (MoE expert path) ----------------
// BK=32, 3-buffer depth-2 pipeline with counted vmcnt + raw s_barrier.
// XCD-aware 1-D grid: bid = x*8 + (g%8) + (g/8)*128, g = y + NY*e.
// MODE 1 (up): NY=64; y: parity selects w_in/w_v plane, y>>1 = col tile. grid 16*64*EE.
// MODE 2 (down): NY=16; y&7 = col tile, y>>3 = K-section (x2). grid 16*16*EE.
template<int MODE>
__global__ __launch_bounds__(256,3) void mgemm(
    const unsigned short* __restrict__ A, const unsigned short* __restrict__ B0b,
    const unsigned short* __restrict__ B1b, size_t bstride,
    float* __restrict__ Cf, unsigned short* __restrict__ Cb0, unsigned short* __restrict__ Cb1,
    int N, int K,
    const int* __restrict__ listb,
    const int* __restrict__ countb, const int* __restrict__ basep)
{
  int bid = blockIdx.x;
  int qq = bid >> 7, rr = bid & 127;
  int xti = rr >> 3, sbit = rr & 7;
  int g = qq*8 + sbit;
  int y, e;
  if (MODE==1){ y = g & 63; e = g >> 6; }
  else        { y = g & 15; e = g >> 4; }

  int M = countb[e];
  int row0 = xti*128;
  if (row0 >= M) return;
  int which = 0, col0, kbase = 0, KL = K;
  const unsigned short* B;
  if (MODE==1){
    which = y & 1;
    col0 = (y >> 1)*128;
    B = (which ? B1b : B0b) + bstride*e;
  } else {
    col0 = (y & 7)*128;
    kbase = (y >> 3)*(K/2);
    KL = K/2;
    B = B0b + bstride*e;
  }
  int slot = basep ? basep[e] : 0;
  const int* rowlist = listb + e*TT;

  __shared__ __align__(16) unsigned short lds[3][2][4096];

  int t = threadIdx.x;
  int lane = t&63, w = t>>6, wr = w>>1, wc = w&1;
  int sr = t>>2, seg = t&3;

  size_t arow[2], brow[2];
#pragma unroll
  for (int i=0;i<2;i++){
    int r = row0 + sr + i*64;
    int rc = (r < M) ? r : (M-1);
    if (MODE==1) arow[i] = (size_t)rowlist[rc];
    else         arow[i] = (size_t)(slot + rc);
    brow[i] = (size_t)(col0 + sr + i*64);
  }

  f32x4 acc[4][4];
#pragma unroll
  for (int m=0;m<4;m++)
#pragma unroll
    for (int n=0;n<4;n++) acc[m][n]=f32x4{0,0,0,0};

  int l15 = lane&15, l4 = lane>>4;

  auto stage = [&](int buf, int k0){
#pragma unroll
    for (int i=0;i<2;i++){
      int ldso = (sr + i*64)*32 + seg*8;
      gl_lds16(A + arow[i]*K + kbase + k0 + seg*8, &lds[buf][0][0] + ldso);
      gl_lds16(B + brow[i]*K + kbase + k0 + seg*8, &lds[buf][1][0] + ldso);
    }
  };

  int NIT = KL/32;
  stage(0, 0);
  if (NIT > 1) stage(1, 32);

  for (int it=0; it<NIT; it++){
    if (it+1 < NIT) asm volatile("s_waitcnt vmcnt(4)" ::: "memory");
    else            asm volatile("s_waitcnt vmcnt(0)" ::: "memory");
    __builtin_amdgcn_s_barrier();
    if (it+2 < NIT) stage((it+2)%3, (it+2)*32);

    int cb = it%3;
    const unsigned short* La = &lds[cb][0][0];
    const unsigned short* Lb = &lds[cb][1][0];
    bf16x8 af[4], bf[4];
#pragma unroll
    for (int m=0;m<4;m++)
      af[m] = *reinterpret_cast<const bf16x8*>(La + (wr*64 + m*16 + l15)*32 + l4*8);
#pragma unroll
    for (int n=0;n<4;n++)
      bf[n] = *reinterpret_cast<const bf16x8*>(Lb + (wc*64 + n*16 + l15)*32 + l4*8);
#pragma unroll
    for (int m=0;m<4;m++)
#pragma unroll
      for (int n=0;n<4;n++)
        acc[m][n] = __builtin_amdgcn_mfma_f32_16x16x32_bf16(af[m], bf[n], acc[m][n], 0,0,0);
  }

  unsigned short* Cb = which ? Cb1 : Cb0;
#pragma unroll
  for (int m=0;m<4;m++){
    int rb = wr*64 + m*16 + l4*4;
#pragma unroll
    for (int n=0;n<4;n++){
      int col = col0 + wc*64 + n*16 + l15;
#pragma unroll
      for (int r=0;r<4;r++){
        int row = row0 + rb + r;
        if (row >= M) continue;
        float v = acc[m][n][r];
        if (MODE==1){
          Cb[(size_t)(slot+row)*N + col] = f2bf(v);
        } else {
          atomicAdd(&Cf[(size_t)rowlist[row]*N + col], v);
        }
      }
    }
  }
}

} // namespace

extern "C" void kernel_launch(void* const* d_in, const int* in_sizes, int n_in,
                              void* d_out, int out_size, void* d_ws, size_t ws_size,
                              hipStream_t stream) {
  const float* hidden = (const float*)d_in[0];
  const int*   mask   = (const int*)d_in[1];
  const int*   pos    = (const int*)d_in[2];
  const float* q_w    = (const float*)d_in[3];
  const float* k_w    = (const float*)d_in[4];
  const float* v_w    = (const float*)d_in[5];
  const float* o_w    = (const float*)d_in[6];
  const float* pre_attn_scale  = (const float*)d_in[7];
  const float* post_attn_scale = (const float*)d_in[8];
  const float* pre_moe_scale   = (const float*)d_in[9];
  const float* post_moe_scale  = (const float*)d_in[10];
  const float* gate_w = (const float*)d_in[11];
  const float* w_in   = (const float*)d_in[12];
  const float* w_v    = (const float*)d_in[13];
  const float* w_out  = (const float*)d_in[14];
  float* out = (float*)d_out;

  char* base = (char*)d_ws;
  auto carve = [&](size_t bytes)->char*{
    char* r = base; base += (bytes + 255) & ~(size_t)255; return r;
  };
  float* hn  = (float*)carve((size_t)TT*HH*4);
  unsigned short* hnb = (unsigned short*)carve((size_t)TT*HH*2);
  unsigned short* hnh = (unsigned short*)carve((size_t)TT*HH*2);
  unsigned short* hnl = (unsigned short*)carve((size_t)TT*HH*2);
  float* qkvb = (float*)carve((size_t)TT*QKV*4);
  unsigned short* qsh = (unsigned short*)carve((size_t)TT*NH*DH*2);
  unsigned short* qsl = (unsigned short*)carve((size_t)TT*NH*DH*2);
  unsigned short* ksh = (unsigned short*)carve((size_t)TT*NKV*DH*2);
  unsigned short* ksl = (unsigned short*)carve((size_t)TT*NKV*DH*2);
  unsigned short* vth = (unsigned short*)carve((size_t)TT*NKV*DH*2);
  unsigned short* vtl = (unsigned short*)carve((size_t)TT*NKV*DH*2);
  unsigned short* ctxh = (unsigned short*)carve((size_t)TT*NH*DH*2);
  unsigned short* ctxl = (unsigned short*)carve((size_t)TT*NH*DH*2);
  float* ao  = (float*)carve((size_t)TT*HH*4);
  float* xb  = (float*)carve((size_t)TT*HH*4);
  float* moe = (float*)carve((size_t)TT*HH*4);
  float* cw  = (float*)carve((size_t)EE*TT*4);
  float* cw_slot = (float*)carve((size_t)2*TT*4);
  int* counts = (int*)carve(64*4);
  int* bases  = (int*)carve(64*4);
  int* lists  = (int*)carve((size_t)EE*TT*4);
  unsigned short* qkvwTh = (unsigned short*)carve((size_t)QKV*HH*2);
  unsigned short* qkvwTl = (unsigned short*)carve((size_t)QKV*HH*2);
  unsigned short* owTh = (unsigned short*)carve((size_t)NH*DH*HH*2);
  unsigned short* owTl = (unsigned short*)carve((size_t)NH*DH*HH*2);
  unsigned short* ehb   = (unsigned short*)carve((size_t)2*TT*II*2);
  unsigned short* tmp0  = (unsigned short*)carve((size_t)2*TT*II*2);
  unsigned short* tmp1  = (unsigned short*)carve((size_t)2*TT*II*2);
  unsigned short* winT  = (unsigned short*)carve((size_t)EE*II*HH*2);
  unsigned short* wvT   = (unsigned short*)carve((size_t)EE*II*HH*2);
  unsigned short* woutT = (unsigned short*)carve((size_t)EE*HH*II*2);
  size_t estride = (size_t)II*HH;

  // ---- attention block (split-bf16, fp32-accurate) ----
  rmsnorm_kernel<<<TT,256,0,stream>>>(hidden, pre_attn_scale, nullptr, nullptr, hnh, hnl);
  transpose_cvt_split<<<dim3(16,16),256,0,stream>>>(q_w, qkvwTh, qkvwTl, HH, NH*DH);
  transpose_cvt_split<<<dim3(16,4), 256,0,stream>>>(k_w, qkvwTh + (size_t)1024*HH, qkvwTl + (size_t)1024*HH, HH, NKV*DH);
  transpose_cvt_split<<<dim3(16,4), 256,0,stream>>>(v_w, qkvwTh + (size_t)1280*HH, qkvwTl + (size_t)1280*HH, HH, NKV*DH);
  transpose_cvt_split<<<dim3(16,16),256,0,stream>>>(o_w, owTh, owTl, NH*DH, HH);

  // qkv: NY=12 col tiles -> pad grid to 2*128; o: NY=8 -> exactly 128
  mgemm_split<<<2*128,256,0,stream>>>(hnh, hnl, qkvwTh, qkvwTl, qkvb, QKV/128, QKV, HH);

  rope_split_kernel<<<(TT*NH*32+255)/256,256,0,stream>>>(qkvb, QKV, 0, pos, qsh, qsl, NH);
  rope_split_kernel<<<(TT*NKV*32+255)/256,256,0,stream>>>(qkvb, QKV, 1024, pos, ksh, ksl, NKV);
  vt_split_kernel<<<dim3(SS/64,NKV,BB),256,0,stream>>>(qkvb, QKV, 1280, vth, vtl);

  attn_mfma<<<dim3(SS/64,NH,BB),256,0,stream>>>(qsh, qsl, ksh, ksl, vth, vtl, mask, ctxh, ctxl);

  mgemm_split<<<128,256,0,stream>>>(ctxh, ctxl, owTh, owTl, ao, HH/128, HH, NH*DH);
  rmsnorm_kernel<<<TT,256,0,stream>>>(ao, post_attn_scale, ao, nullptr, nullptr, nullptr);
  add_kernel<<<(TT*HH)/256,256,0,stream>>>(hidden, ao, xb, TT*HH);

  // ---- MoE block (routing fp32, experts bf16) ----
  rmsnorm_kernel<<<TT,256,0,stream>>>(xb, pre_moe_scale, hn, hnb, nullptr, nullptr);
  hipMemsetAsync(counts, 0, 64*sizeof(int), stream);
  hipMemsetAsync(moe, 0, (size_t)TT*HH*sizeof(float), stream);
  route_kernel<<<TT,64,0,stream>>>(hn, gate_w, counts, lists, cw);
  prefix_kernel<<<1,64,0,stream>>>(counts, bases, cw, cw_slot);

  // batched expert-weight transposes (one dispatch per weight tensor)
  transpose_cvt<<<dim3(16,64,EE),256,0,stream>>>(w_in, winT, HH, II, (size_t)HH*II, estride);
  transpose_cvt<<<dim3(16,64,EE),256,0,stream>>>(w_v,  wvT,  HH, II, (size_t)HH*II, estride);
  transpose_cvt<<<dim3(64,16,EE),256,0,stream>>>(w_out, woutT, II, HH, (size_t)II*HH, estride);

  // up: XCD-remapped 1-D grid, 16 row-tiles x 64 (plane|col) x 8 experts
  mgemm<1><<<16*64*EE,256,0,stream>>>(hnb, winT, wvT, estride, nullptr, tmp0, tmp1,
      II, HH, lists, counts, bases);
  moe_combine<<<2*TT,256,0,stream>>>(tmp0, tmp1, cw_slot, bases+EE, ehb);
  // down: XCD-remapped 1-D grid, 16 row-tiles x 16 (col|ksec) x 8 experts, K-split x2
  mgemm<2><<<16*16*EE,256,0,stream>>>(ehb, woutT, nullptr, estride, moe, nullptr, nullptr,
      HH, II, lists, counts, bases);

  rmsnorm_kernel<<<TT,256,0,stream>>>(moe, post_moe_scale, moe, nullptr, nullptr, nullptr);
  add_kernel<<<(TT*HH)/256,256,0,stream>>>(xb, moe, out, TT*HH);
}

// Round 14
// 607.011 us; speedup vs baseline: 1.7597x; 1.0430x over previous
//
#include <hip/hip_runtime.h>
#include <hip/hip_bf16.h>
#include <math.h>

namespace {

constexpr int BB=2, SS=1024, HH=1024, NH=16, NKV=4, DH=64;
constexpr int II=4096, EE=8;
constexpr int TT=BB*SS;
constexpr int QKV=1536;                 // merged projection width: 1024 q + 256 k + 256 v
constexpr float EPS=1e-5f;

typedef __bf16 bf16x8 __attribute__((ext_vector_type(8)));
typedef float f32x4 __attribute__((ext_vector_type(4)));

__device__ __forceinline__ unsigned short f2bf(float x){
  union { float f; unsigned u; } un; un.f = x;
  unsigned r = un.u + 0x7fffu + ((un.u>>16)&1u);
  return (unsigned short)(r>>16);
}
__device__ __forceinline__ float bfval(unsigned short h){
  union { unsigned u; float f; } r; r.u = ((unsigned)h)<<16; return r.f;
}
__device__ __forceinline__ void split2(float v, unsigned short& hi, unsigned short& lo){
  hi = f2bf(v);
  lo = f2bf(v - bfval(hi));
}

__device__ __forceinline__ void gl_lds16(const void* g, void* l){
  __builtin_amdgcn_global_load_lds(
    (const __attribute__((address_space(1))) unsigned int*)g,
    (__attribute__((address_space(3))) unsigned int*)l, 16, 0, 0);
}

__device__ __forceinline__ float gelu_tanh(float x){
  float x3 = x*x*x;
  return 0.5f*x*(1.f + tanhf(0.7978845608028654f*(x + 0.044715f*x3)));
}

// ---------------- RMSNorm: optional fp32 / bf16 / split outputs ----------------
__global__ void rmsnorm_kernel(const float* __restrict__ in, const float* __restrict__ scale,
                               float* __restrict__ outf, unsigned short* __restrict__ outb,
                               unsigned short* __restrict__ outh, unsigned short* __restrict__ outl){
  int row = blockIdx.x, tid = threadIdx.x;
  const float* x = in + (size_t)row*HH;
  float ss = 0.f;
  for (int i=tid;i<HH;i+=256){ float v=x[i]; ss+=v*v; }
  __shared__ float red[256];
  red[tid]=ss; __syncthreads();
  for (int s=128;s>0;s>>=1){ if(tid<s) red[tid]+=red[tid+s]; __syncthreads(); }
  float inv = rsqrtf(red[0]/(float)HH + EPS);
  for (int i=tid;i<HH;i+=256){
    float v = x[i]*inv*scale[i];
    size_t o = (size_t)row*HH+i;
    if (outf) outf[o]=v;
    if (outb) outb[o]=f2bf(v);
    if (outh){ unsigned short h,l; split2(v,h,l); outh[o]=h; outl[o]=l; }
  }
}

// xb = hidden + rmsnorm(ao_raw)*post_scale ; hn/hnb = rmsnorm(xb)*pre_scale
__global__ void fuse_attn_post(const float* __restrict__ ao_raw, const float* __restrict__ hidden,
                               const float* __restrict__ post_scale, const float* __restrict__ pre_scale,
                               float* __restrict__ xb, float* __restrict__ hn,
                               unsigned short* __restrict__ hnb){
  int row = blockIdx.x, tid = threadIdx.x;
  const float* a = ao_raw + (size_t)row*HH;
  const float* h = hidden + (size_t)row*HH;
  float av[4], hv[4];
  float ss = 0.f;
#pragma unroll
  for (int i=0;i<4;i++){
    int idx = tid + i*256;
    av[i]=a[idx]; hv[i]=h[idx];
    ss += av[i]*av[i];
  }
  __shared__ float red[256];
  red[tid]=ss; __syncthreads();
  for (int s=128;s>0;s>>=1){ if(tid<s) red[tid]+=red[tid+s]; __syncthreads(); }
  float inv1 = rsqrtf(red[0]/(float)HH + EPS);
  __syncthreads();
  float xv[4]; float ss2=0.f;
#pragma unroll
  for (int i=0;i<4;i++){
    int idx = tid + i*256;
    xv[i] = hv[i] + av[i]*inv1*post_scale[idx];
    ss2 += xv[i]*xv[i];
  }
  red[tid]=ss2; __syncthreads();
  for (int s=128;s>0;s>>=1){ if(tid<s) red[tid]+=red[tid+s]; __syncthreads(); }
  float inv2 = rsqrtf(red[0]/(float)HH + EPS);
#pragma unroll
  for (int i=0;i<4;i++){
    int idx = tid + i*256;
    size_t o = (size_t)row*HH + idx;
    xb[o] = xv[i];
    float v = xv[i]*inv2*pre_scale[idx];
    hn[o] = v;
    hnb[o] = f2bf(v);
  }
}

// out = xb + rmsnorm(moe)*scale
__global__ void fuse_moe_post(const float* __restrict__ moe, const float* __restrict__ xb,
                              const float* __restrict__ scale, float* __restrict__ out){
  int row = blockIdx.x, tid = threadIdx.x;
  const float* m = moe + (size_t)row*HH;
  float mv[4]; float ss=0.f;
#pragma unroll
  for (int i=0;i<4;i++){
    int idx = tid + i*256;
    mv[i]=m[idx]; ss += mv[i]*mv[i];
  }
  __shared__ float red[256];
  red[tid]=ss; __syncthreads();
  for (int s=128;s>0;s>>=1){ if(tid<s) red[tid]+=red[tid+s]; __syncthreads(); }
  float inv = rsqrtf(red[0]/(float)HH + EPS);
#pragma unroll
  for (int i=0;i<4;i++){
    int idx = tid + i*256;
    size_t o = (size_t)row*HH + idx;
    out[o] = xb[o] + mv[i]*inv*scale[idx];
  }
}

// ---------------- RoPE from merged proj buffer -> split bf16 planes ----------------
__global__ void rope_split_kernel(const float* __restrict__ x, int stride, int off,
                                  const int* __restrict__ pos_ids,
                                  unsigned short* __restrict__ oh, unsigned short* __restrict__ ol,
                                  int nheads){
  int idx = blockIdx.x*256 + threadIdx.x;
  int total = TT*nheads*32;
  if (idx >= total) return;
  int j = idx & 31;
  int hh = (idx>>5) % nheads;
  int t = idx / (32*nheads);
  float pos = (float)pos_ids[t];
  float inv_freq = powf(10000.f, -(float)j/32.f);
  float ang = pos * inv_freq;
  float s, c; sincosf(ang, &s, &c);
  const float* p = x + (size_t)t*stride + off + hh*DH;
  float x1 = p[j], x2 = p[j+32];
  float r1 = x1*c - x2*s;
  float r2 = x2*c + x1*s;
  size_t o = ((size_t)t*nheads + hh)*DH;
  unsigned short h1,l1,h2,l2;
  split2(r1,h1,l1); split2(r2,h2,l2);
  oh[o+j]=h1;    ol[o+j]=l1;
  oh[o+j+32]=h2; ol[o+j+32]=l2;
}

// ---------------- V transpose (from merged proj) -> split bf16 Vt[b][kvh][d][S] ----------------
__global__ __launch_bounds__(256) void vt_split_kernel(const float* __restrict__ src, int stride, int off,
    unsigned short* __restrict__ vth, unsigned short* __restrict__ vtl){
  int k0 = blockIdx.x*64;
  int kvh = blockIdx.y;
  int b = blockIdx.z;
  __shared__ float tile[64][65];
  int t = threadIdx.x;
  int c4 = (t&15)*4, gg = t>>4;
#pragma unroll
  for (int r=0;r<4;r++){
    int kk = gg + r*16;
    float4 v = *reinterpret_cast<const float4*>(src + (size_t)(b*SS+k0+kk)*stride + off + kvh*DH + c4);
    tile[kk][c4]=v.x; tile[kk][c4+1]=v.y; tile[kk][c4+2]=v.z; tile[kk][c4+3]=v.w;
  }
  __syncthreads();
#pragma unroll
  for (int r=0;r<4;r++){
    int dd = gg + r*16;
    ushort4 h4, l4v;
    split2(tile[c4  ][dd], h4.x, l4v.x);
    split2(tile[c4+1][dd], h4.y, l4v.y);
    split2(tile[c4+2][dd], h4.z, l4v.z);
    split2(tile[c4+3][dd], h4.w, l4v.w);
    size_t o = ((size_t)(b*NKV+kvh)*DH + dd)*SS + k0 + c4;
    *reinterpret_cast<ushort4*>(vth+o)=h4;
    *reinterpret_cast<ushort4*>(vtl+o)=l4v;
  }
}

// ---------------- MFMA flash attention (split-bf16, fp32-accurate) ----------------
__global__ __launch_bounds__(256) void attn_mfma(
    const unsigned short* __restrict__ qh, const unsigned short* __restrict__ ql,
    const unsigned short* __restrict__ khp, const unsigned short* __restrict__ klp,
    const unsigned short* __restrict__ vth, const unsigned short* __restrict__ vtl,
    const int* __restrict__ amask,
    unsigned short* __restrict__ ctxh, unsigned short* __restrict__ ctxl)
{
  int qb = blockIdx.x, h = blockIdx.y, b = blockIdx.z;
  int kvh = h >> 2;
  int tid = threadIdx.x;
  int w = tid >> 6, lane = tid & 63;
  int g = lane >> 4, l15 = lane & 15;

  __shared__ __align__(16) unsigned short Klh[64*64];
  __shared__ __align__(16) unsigned short Kll[64*64];
  __shared__ __align__(16) unsigned short Vlh[64*64];
  __shared__ __align__(16) unsigned short Vll[64*64];
  __shared__ __align__(16) unsigned short Pst[4][2][16*72];

  int q0w = qb*64 + w*16;

  bf16x8 qfh[2], qfl[2];
  {
    size_t qrow = ((size_t)(b*SS + q0w + l15)*NH + h)*DH;
#pragma unroll
    for (int ks=0; ks<2; ks++){
      qfh[ks] = *reinterpret_cast<const bf16x8*>(qh + qrow + ks*32 + g*8);
      qfl[ks] = *reinterpret_cast<const bf16x8*>(ql + qrow + ks*32 + g*8);
    }
  }

  f32x4 acc[4];
  float m_run[4], l_run[4];
#pragma unroll
  for (int i=0;i<4;i++){ acc[i]=f32x4{0,0,0,0}; m_run[i]=-1e30f; l_run[i]=0.f; }

  int nkv = qb + 1;
  for (int kblk=0; kblk<nkv; kblk++){
    int k0 = kblk*64;
    __syncthreads();
#pragma unroll
    for (int shot=0; shot<2; shot++){
      int a = shot*256 + tid;
      int row = a>>3, seg = a&7;
      int ss8 = (seg ^ (row&7))*8;
      int lo = row*64 + seg*8;
      size_t kg = ((size_t)(b*SS + k0 + row)*NKV + kvh)*DH + ss8;
      size_t vg = ((size_t)(b*NKV + kvh)*DH + row)*SS + k0 + ss8;
      gl_lds16(khp + kg, Klh + lo);
      gl_lds16(klp + kg, Kll + lo);
      gl_lds16(vth + vg, Vlh + lo);
      gl_lds16(vtl + vg, Vll + lo);
    }
    __syncthreads();

    f32x4 sf[4];
#pragma unroll
    for (int nf=0;nf<4;nf++) sf[nf]=f32x4{0,0,0,0};
#pragma unroll
    for (int ks=0; ks<2; ks++){
#pragma unroll
      for (int nf=0; nf<4; nf++){
        int krow = nf*16 + l15;
        int off = krow*64 + (((ks*4+g) ^ (krow&7))*8);
        bf16x8 bh = *reinterpret_cast<const bf16x8*>(Klh + off);
        bf16x8 bl = *reinterpret_cast<const bf16x8*>(Kll + off);
        sf[nf] = __builtin_amdgcn_mfma_f32_16x16x32_bf16(qfh[ks], bh, sf[nf],0,0,0);
        sf[nf] = __builtin_amdgcn_mfma_f32_16x16x32_bf16(qfh[ks], bl, sf[nf],0,0,0);
        sf[nf] = __builtin_amdgcn_mfma_f32_16x16x32_bf16(qfl[ks], bh, sf[nf],0,0,0);
      }
    }

    int am4[4];
#pragma unroll
    for (int nf=0;nf<4;nf++) am4[nf] = amask[b*SS + k0 + nf*16 + l15];
#pragma unroll
    for (int nf=0;nf<4;nf++){
      int k_abs = k0 + nf*16 + l15;
#pragma unroll
      for (int r=0;r<4;r++){
        float s = sf[nf][r]*0.125f;
        int q_abs = q0w + g*4 + r;
        if (k_abs > q_abs || am4[nf] <= 0) s = -1e9f;
        sf[nf][r] = s;
      }
    }

    float m_new[4], fsc[4];
#pragma unroll
    for (int r=0;r<4;r++){
      float v = fmaxf(fmaxf(sf[0][r],sf[1][r]), fmaxf(sf[2][r],sf[3][r]));
#pragma unroll
      for (int o=1;o<16;o<<=1) v = fmaxf(v, __shfl_xor(v,o));
      m_new[r] = fmaxf(m_run[r], v);
      fsc[r] = expf(m_run[r] - m_new[r]);
      m_run[r] = m_new[r];
    }

    unsigned short* Ph  = Pst[w][0];
    unsigned short* Plo = Pst[w][1];
    float rsum[4] = {0.f,0.f,0.f,0.f};
#pragma unroll
    for (int nf=0;nf<4;nf++){
#pragma unroll
      for (int r=0;r<4;r++){
        float p = expf(sf[nf][r] - m_new[r]);
        rsum[r] += p;
        unsigned short hi = f2bf(p);
        float lo = p - bfval(hi);
        Ph [(g*4+r)*72 + nf*16 + l15] = hi;
        Plo[(g*4+r)*72 + nf*16 + l15] = f2bf(lo);
      }
    }
#pragma unroll
    for (int r=0;r<4;r++){
#pragma unroll
      for (int o=1;o<16;o<<=1) rsum[r] += __shfl_xor(rsum[r],o);
      l_run[r] = l_run[r]*fsc[r] + rsum[r];
#pragma unroll
      for (int nf=0;nf<4;nf++) acc[nf][r] *= fsc[r];
    }

#pragma unroll
    for (int ks=0; ks<2; ks++){
      bf16x8 pa = *reinterpret_cast<const bf16x8*>(Ph  + l15*72 + ks*32 + g*8);
      bf16x8 pl = *reinterpret_cast<const bf16x8*>(Plo + l15*72 + ks*32 + g*8);
#pragma unroll
      for (int nf=0; nf<4; nf++){
        int drow = nf*16 + l15;
        int off = drow*64 + (((ks*4+g) ^ (drow&7))*8);
        bf16x8 vh = *reinterpret_cast<const bf16x8*>(Vlh + off);
        bf16x8 vl = *reinterpret_cast<const bf16x8*>(Vll + off);
        acc[nf] = __builtin_amdgcn_mfma_f32_16x16x32_bf16(pa, vh, acc[nf],0,0,0);
        acc[nf] = __builtin_amdgcn_mfma_f32_16x16x32_bf16(pa, vl, acc[nf],0,0,0);
        acc[nf] = __builtin_amdgcn_mfma_f32_16x16x32_bf16(pl, vh, acc[nf],0,0,0);
      }
    }
  }

#pragma unroll
  for (int r=0;r<4;r++){
    float inv = 1.f / l_run[r];
    size_t orow = ((size_t)(b*SS + q0w + g*4 + r)*NH + h)*DH;
#pragma unroll
    for (int nf=0;nf<4;nf++){
      float v = acc[nf][r]*inv;
      unsigned short hi,lo; split2(v,hi,lo);
      ctxh[orow + nf*16 + l15] = hi;
      ctxl[orow + nf*16 + l15] = lo;
    }
  }
}

// ---------------- MoE routing ----------------
__global__ void route_kernel(const float* __restrict__ x, const float* __restrict__ gw,
                             int* __restrict__ counts, int* __restrict__ lists,
                             float* __restrict__ cw){
  int t = blockIdx.x;
  int lane = threadIdx.x;
  float acc[EE];
#pragma unroll
  for (int e=0;e<EE;e++) acc[e]=0.f;
  for (int hh=lane; hh<HH; hh+=64){
    float xv = x[(size_t)t*HH + hh];
#pragma unroll
    for (int e=0;e<EE;e++) acc[e] += xv*gw[hh*EE+e];
  }
#pragma unroll
  for (int e=0;e<EE;e++){
#pragma unroll
    for (int off=1; off<64; off<<=1) acc[e] += __shfl_xor(acc[e], off);
  }
  if (lane==0){
    float m = acc[0];
    for (int e=1;e<EE;e++) m = fmaxf(m, acc[e]);
    float p[EE], s=0.f;
    for (int e=0;e<EE;e++){ p[e]=expf(acc[e]-m); s+=p[e]; }
    float invs = 1.f/s;
    for (int e=0;e<EE;e++) p[e]*=invs;
    int i1=0;
    for (int e=1;e<EE;e++) if (p[e]>p[i1]) i1=e;
    int i2 = (i1==0)?1:0;
    for (int e=0;e<EE;e++) if (e!=i1 && p[e]>p[i2]) i2=e;
    int pos = atomicAdd(&counts[i1],1);
    lists[i1*TT+pos]=t; cw[i1*TT+pos]=p[i1];
    pos = atomicAdd(&counts[i2],1);
    lists[i2*TT+pos]=t; cw[i2*TT+pos]=p[i2];
  }
}

// prefix over experts + slot-indexed gate weights; bases[EE] = total
__global__ void prefix_kernel(const int* __restrict__ c, int* __restrict__ b,
                              const float* __restrict__ cw, float* __restrict__ cw_slot){
  int lane = threadIdx.x;
  __shared__ int sb[EE+1];
  if (lane==0){
    int s=0;
    for (int e=0;e<EE;e++){ sb[e]=s; b[e]=s; s+=c[e]; }
    sb[EE]=s; b[EE]=s;
  }
  __syncthreads();
  for (int e=0;e<EE;e++){
    int cnt=c[e], base=sb[e];
    for (int i=lane;i<cnt;i+=64) cw_slot[base+i]=cw[e*TT+i];
  }
}

// ehb = bf16( gelu(tmp0) * tmp1 * cw_slot[row] )
__global__ void moe_combine(const unsigned short* __restrict__ t0,
                            const unsigned short* __restrict__ t1,
                            const float* __restrict__ cwslot,
                            const int* __restrict__ ntotp,
                            unsigned short* __restrict__ ehb){
  int row = blockIdx.x;
  if (row >= *ntotp) return;
  float c = cwslot[row];
  size_t base = (size_t)row*II;
  int tid = threadIdx.x;
  for (int c0 = tid*8; c0 < II; c0 += 256*8){
    ushort4 x0 = *reinterpret_cast<const ushort4*>(t0+base+c0);
    ushort4 x1 = *reinterpret_cast<const ushort4*>(t0+base+c0+4);
    ushort4 y0 = *reinterpret_cast<const ushort4*>(t1+base+c0);
    ushort4 y1 = *reinterpret_cast<const ushort4*>(t1+base+c0+4);
    ushort4 o0, o1;
    o0.x = f2bf(gelu_tanh(bfval(x0.x))*bfval(y0.x)*c);
    o0.y = f2bf(gelu_tanh(bfval(x0.y))*bfval(y0.y)*c);
    o0.z = f2bf(gelu_tanh(bfval(x0.z))*bfval(y0.z)*c);
    o0.w = f2bf(gelu_tanh(bfval(x0.w))*bfval(y0.w)*c);
    o1.x = f2bf(gelu_tanh(bfval(x1.x))*bfval(y1.x)*c);
    o1.y = f2bf(gelu_tanh(bfval(x1.y))*bfval(y1.y)*c);
    o1.z = f2bf(gelu_tanh(bfval(x1.z))*bfval(y1.z)*c);
    o1.w = f2bf(gelu_tanh(bfval(x1.w))*bfval(y1.w)*c);
    *reinterpret_cast<ushort4*>(ehb+base+c0)   = o0;
    *reinterpret_cast<ushort4*>(ehb+base+c0+4) = o1;
  }
}

// ---------------- transpose + fp32->bf16 (single plane), batched over z ----------------
__global__ __launch_bounds__(256) void transpose_cvt(const float* __restrict__ in,
    unsigned short* __restrict__ out, int K, int N, size_t in_zstride, size_t out_zstride){
  __shared__ float tile[64][65];
  int k0 = blockIdx.x*64, n0 = blockIdx.y*64;
  const float* inz = in + in_zstride*blockIdx.z;
  unsigned short* outz = out + out_zstride*blockIdx.z;
  int t = threadIdx.x;
  int c4 = (t&15)*4, g = t>>4;
#pragma unroll
  for (int r=0;r<4;r++){
    int kk = g + r*16;
    float4 v = *reinterpret_cast<const float4*>(inz + (size_t)(k0+kk)*N + n0 + c4);
    tile[kk][c4]=v.x; tile[kk][c4+1]=v.y; tile[kk][c4+2]=v.z; tile[kk][c4+3]=v.w;
  }
  __syncthreads();
#pragma unroll
  for (int r=0;r<4;r++){
    int nn = g + r*16;
    ushort4 o;
    o.x=f2bf(tile[c4][nn]);   o.y=f2bf(tile[c4+1][nn]);
    o.z=f2bf(tile[c4+2][nn]); o.w=f2bf(tile[c4+3][nn]);
    *reinterpret_cast<ushort4*>(outz + (size_t)(n0+nn)*K + k0 + c4) = o;
  }
}

// ---------------- transpose + split hi/lo ----------------
__global__ __launch_bounds__(256) void transpose_cvt_split(const float* __restrict__ in,
    unsigned short* __restrict__ oh, unsigned short* __restrict__ ol, int K, int N){
  __shared__ float tile[64][65];
  int k0 = blockIdx.x*64, n0 = blockIdx.y*64;
  int t = threadIdx.x;
  int c4 = (t&15)*4, g = t>>4;
#pragma unroll
  for (int r=0;r<4;r++){
    int kk = g + r*16;
    float4 v = *reinterpret_cast<const float4*>(in + (size_t)(k0+kk)*N + n0 + c4);
    tile[kk][c4]=v.x; tile[kk][c4+1]=v.y; tile[kk][c4+2]=v.z; tile[kk][c4+3]=v.w;
  }
  __syncthreads();
#pragma unroll
  for (int r=0;r<4;r++){
    int nn = g + r*16;
    ushort4 h4, l4v;
    split2(tile[c4  ][nn], h4.x, l4v.x);
    split2(tile[c4+1][nn], h4.y, l4v.y);
    split2(tile[c4+2][nn], h4.z, l4v.z);
    split2(tile[c4+3][nn], h4.w, l4v.w);
    size_t o = (size_t)(n0+nn)*K + k0 + c4;
    *reinterpret_cast<ushort4*>(oh + o) = h4;
    *reinterpret_cast<ushort4*>(ol + o) = l4v;
  }
}

// ---------------- split-bf16 3-term MFMA GEMM, dbuf, XCD-remapped grid, swizzled LDS ----------------
// swizzle: LDS[row][p] = global chunk p ^ ((row>>1)&3); read chunk c at p = c ^ ((row>>1)&3).
__global__ __launch_bounds__(256,2) void mgemm_split(
    const unsigned short* __restrict__ Ah, const unsigned short* __restrict__ Alo,
    const unsigned short* __restrict__ Bh, const unsigned short* __restrict__ Blo,
    float* __restrict__ Cf, int NY, int N, int K)
{
  int bid = blockIdx.x;
  int qq = bid >> 7, rr = bid & 127;
  int xti = rr >> 3, sbit = rr & 7;
  int g = qq*8 + sbit;
  if (g >= NY) return;
  int row0 = xti*128, col0 = g*128;
  __shared__ __align__(16) unsigned short lds[32768];   // 2 bufs x 4 planes x 4096

  int t = threadIdx.x;
  int lane = t&63, w = t>>6, wr = w>>1, wc = w&1;
  int sr = t>>2, seg = t&3;
  int swzs = (t>>3)&3;                 // ((sr)>>1)&3

  f32x4 acc[4][4];
#pragma unroll
  for (int m=0;m<4;m++)
#pragma unroll
    for (int n=0;n<4;n++) acc[m][n]=f32x4{0,0,0,0};

  int l15 = lane&15, l4 = lane>>4;
  int swzr = (l15>>1)&3;

  auto stage = [&](int buf, int k0){
    unsigned short* Lb = lds + buf*16384;
    int ksw = (seg ^ swzs)*8;
#pragma unroll
    for (int i=0;i<2;i++){
      int ldso = (sr + i*64)*32 + seg*8;
      size_t ar = (size_t)(row0 + sr + i*64);
      size_t br = (size_t)(col0 + sr + i*64);
      gl_lds16(Ah  + ar*K + k0 + ksw, Lb +         ldso);
      gl_lds16(Alo + ar*K + k0 + ksw, Lb + 4096  + ldso);
      gl_lds16(Bh  + br*K + k0 + ksw, Lb + 8192  + ldso);
      gl_lds16(Blo + br*K + k0 + ksw, Lb + 12288 + ldso);
    }
  };

  stage(0, 0);
  __syncthreads();
  int cur = 0;
  int NIT = K/32;
  int cofs = (l4 ^ swzr)*8;
  for (int it=0; it<NIT; it++){
    if (it+1 < NIT) stage(cur^1, (it+1)*32);
    const unsigned short* Lb = lds + cur*16384;
    bf16x8 ah[4], al[4], bh[4], bl[4];
#pragma unroll
    for (int m=0;m<4;m++){
      int ro = (wr*64 + m*16 + l15)*32 + cofs;
      ah[m]=*reinterpret_cast<const bf16x8*>(Lb +        ro);
      al[m]=*reinterpret_cast<const bf16x8*>(Lb + 4096 + ro);
    }
#pragma unroll
    for (int n=0;n<4;n++){
      int ro = (wc*64 + n*16 + l15)*32 + cofs;
      bh[n]=*reinterpret_cast<const bf16x8*>(Lb + 8192  + ro);
      bl[n]=*reinterpret_cast<const bf16x8*>(Lb + 12288 + ro);
    }
#pragma unroll
    for (int m=0;m<4;m++)
#pragma unroll
      for (int n=0;n<4;n++){
        acc[m][n] = __builtin_amdgcn_mfma_f32_16x16x32_bf16(ah[m], bh[n], acc[m][n], 0,0,0);
        acc[m][n] = __builtin_amdgcn_mfma_f32_16x16x32_bf16(ah[m], bl[n], acc[m][n], 0,0,0);
        acc[m][n] = __builtin_amdgcn_mfma_f32_16x16x32_bf16(al[m], bh[n], acc[m][n], 0,0,0);
      }
    __syncthreads();
    cur ^= 1;
  }

#pragma unroll
  for (int m=0;m<4;m++){
    int rb = wr*64 + m*16 + l4*4;
#pragma unroll
    for (int n=0;n<4;n++){
      int col = col0 + wc*64 + n*16 + l15;
#pragma unroll
      for (int r=0;r<4;r++){
        int row = row0 + rb + r;
        Cf[(size_t)row*N + col] = acc[m][n][r];
      }
    }
  }
}

// ---------------- bf16 MFMA GEMM (MoE expert path) ----------------
// BK=32, 3-buffer counted-vmcnt pipeline, XCD-remapped grid, swizzled LDS (2-way max).
template<int MODE>
__global__ __launch_bounds__(256,3) void mgemm(
    const unsigned short* __restrict__ A, const unsigned short* __restrict__ B0b,
    const unsigned short* __restrict__ B1b, size_t bstride,
    float* __restrict__ Cf, unsigned short* __restrict__ Cb0, unsigned short* __restrict__ Cb1,
    int N, int K,
    const int* __restrict__ listb,
    const int* __restrict__ countb, const int* __restrict__ basep)
{
  int bid = blockIdx.x;
  int qq = bid >> 7, rr = bid & 127;
  int xti = rr >> 3, sbit = rr & 7;
  int g = qq*8 + sbit;
  int y, e;
  if (MODE==1){ y = g & 63; e = g >> 6; }
  else        { y = g & 15; e = g >> 4; }

  int M = countb[e];
  int row0 = xti*128;
  if (row0 >= M) return;
  int which = 0, col0, kbase = 0, KL = K;
  const unsigned short* B;
  if (MODE==1){
    which = y & 1;
    col0 = (y >> 1)*128;
    B = (which ? B1b : B0b) + bstride*e;
  } else {
    col0 = (y & 7)*128;
    kbase = (y >> 3)*(K/2);
    KL = K/2;
    B = B0b + bstride*e;
  }
  int slot = basep ? basep[e] : 0;
  const int* rowlist = listb + e*TT;

  __shared__ __align__(16) unsigned short lds[3][2][4096];

  int t = threadIdx.x;
  int lane = t&63, w = t>>6, wr = w>>1, wc = w&1;
  int sr = t>>2, seg = t&3;
  int swzs = (t>>3)&3;

  size_t arow[2], brow[2];
#pragma unroll
  for (int i=0;i<2;i++){
    int r = row0 + sr + i*64;
    int rc = (r < M) ? r : (M-1);
    if (MODE==1) arow[i] = (size_t)rowlist[rc];
    else         arow[i] = (size_t)(slot + rc);
    brow[i] = (size_t)(col0 + sr + i*64);
  }

  f32x4 acc[4][4];
#pragma unroll
  for (int m=0;m<4;m++)
#pragma unroll
    for (int n=0;n<4;n++) acc[m][n]=f32x4{0,0,0,0};

  int l15 = lane&15, l4 = lane>>4;
  int cofs = (l4 ^ ((l15>>1)&3))*8;

  auto stage = [&](int buf, int k0){
    int ksw = (seg ^ swzs)*8;
#pragma unroll
    for (int i=0;i<2;i++){
      int ldso = (sr + i*64)*32 + seg*8;
      gl_lds16(A + arow[i]*K + kbase + k0 + ksw, &lds[buf][0][0] + ldso);
      gl_lds16(B + brow[i]*K + kbase + k0 + ksw, &lds[buf][1][0] + ldso);
    }
  };

  int NIT = KL/32;
  stage(0, 0);
  if (NIT > 1) stage(1, 32);

  for (int it=0; it<NIT; it++){
    if (it+1 < NIT) asm volatile("s_waitcnt vmcnt(4)" ::: "memory");
    else            asm volatile("s_waitcnt vmcnt(0)" ::: "memory");
    __builtin_amdgcn_s_barrier();
    if (it+2 < NIT) stage((it+2)%3, (it+2)*32);

    int cb = it%3;
    const unsigned short* La = &lds[cb][0][0];
    const unsigned short* Lb = &lds[cb][1][0];
    bf16x8 af[4], bf[4];
#pragma unroll
    for (int m=0;m<4;m++)
      af[m] = *reinterpret_cast<const bf16x8*>(La + (wr*64 + m*16 + l15)*32 + cofs);
#pragma unroll
    for (int n=0;n<4;n++)
      bf[n] = *reinterpret_cast<const bf16x8*>(Lb + (wc*64 + n*16 + l15)*32 + cofs);
#pragma unroll
    for (int m=0;m<4;m++)
#pragma unroll
      for (int n=0;n<4;n++)
        acc[m][n] = __builtin_amdgcn_mfma_f32_16x16x32_bf16(af[m], bf[n], acc[m][n], 0,0,0);
  }

  unsigned short* Cb = which ? Cb1 : Cb0;
#pragma unroll
  for (int m=0;m<4;m++){
    int rb = wr*64 + m*16 + l4*4;
#pragma unroll
    for (int n=0;n<4;n++){
      int col = col0 + wc*64 + n*16 + l15;
#pragma unroll
      for (int r=0;r<4;r++){
        int row = row0 + rb + r;
        if (row >= M) continue;
        float v = acc[m][n][r];
        if (MODE==1){
          Cb[(size_t)(slot+row)*N + col] = f2bf(v);
        } else {
          atomicAdd(&Cf[(size_t)rowlist[row]*N + col], v);
        }
      }
    }
  }
}

} // namespace

extern "C" void kernel_launch(void* const* d_in, const int* in_sizes, int n_in,
                              void* d_out, int out_size, void* d_ws, size_t ws_size,
                              hipStream_t stream) {
  const float* hidden = (const float*)d_in[0];
  const int*   mask   = (const int*)d_in[1];
  const int*   pos    = (const int*)d_in[2];
  const float* q_w    = (const float*)d_in[3];
  const float* k_w    = (const float*)d_in[4];
  const float* v_w    = (const float*)d_in[5];
  const float* o_w    = (const float*)d_in[6];
  const float* pre_attn_scale  = (const float*)d_in[7];
  const float* post_attn_scale = (const float*)d_in[8];
  const float* pre_moe_scale   = (const float*)d_in[9];
  const float* post_moe_scale  = (const float*)d_in[10];
  const float* gate_w = (const float*)d_in[11];
  const float* w_in   = (const float*)d_in[12];
  const float* w_v    = (const float*)d_in[13];
  const float* w_out  = (const float*)d_in[14];
  float* out = (float*)d_out;

  char* base = (char*)d_ws;
  auto carve = [&](size_t bytes)->char*{
    char* r = base; base += (bytes + 255) & ~(size_t)255; return r;
  };
  float* hn  = (float*)carve((size_t)TT*HH*4);
  unsigned short* hnb = (unsigned short*)carve((size_t)TT*HH*2);
  unsigned short* hnh = (unsigned short*)carve((size_t)TT*HH*2);
  unsigned short* hnl = (unsigned short*)carve((size_t)TT*HH*2);
  float* qkvb = (float*)carve((size_t)TT*QKV*4);
  unsigned short* qsh = (unsigned short*)carve((size_t)TT*NH*DH*2);
  unsigned short* qsl = (unsigned short*)carve((size_t)TT*NH*DH*2);
  unsigned short* ksh = (unsigned short*)carve((size_t)TT*NKV*DH*2);
  unsigned short* ksl = (unsigned short*)carve((size_t)TT*NKV*DH*2);
  unsigned short* vth = (unsigned short*)carve((size_t)TT*NKV*DH*2);
  unsigned short* vtl = (unsigned short*)carve((size_t)TT*NKV*DH*2);
  unsigned short* ctxh = (unsigned short*)carve((size_t)TT*NH*DH*2);
  unsigned short* ctxl = (unsigned short*)carve((size_t)TT*NH*DH*2);
  float* ao  = (float*)carve((size_t)TT*HH*4);
  float* xb  = (float*)carve((size_t)TT*HH*4);
  float* moe = (float*)carve((size_t)TT*HH*4);
  float* cw  = (float*)carve((size_t)EE*TT*4);
  float* cw_slot = (float*)carve((size_t)2*TT*4);
  int* counts = (int*)carve(64*4);
  int* bases  = (int*)carve(64*4);
  int* lists  = (int*)carve((size_t)EE*TT*4);
  unsigned short* qkvwTh = (unsigned short*)carve((size_t)QKV*HH*2);
  unsigned short* qkvwTl = (unsigned short*)carve((size_t)QKV*HH*2);
  unsigned short* owTh = (unsigned short*)carve((size_t)NH*DH*HH*2);
  unsigned short* owTl = (unsigned short*)carve((size_t)NH*DH*HH*2);
  unsigned short* ehb   = (unsigned short*)carve((size_t)2*TT*II*2);
  unsigned short* tmp0  = (unsigned short*)carve((size_t)2*TT*II*2);
  unsigned short* tmp1  = (unsigned short*)carve((size_t)2*TT*II*2);
  unsigned short* winT  = (unsigned short*)carve((size_t)EE*II*HH*2);
  unsigned short* wvT   = (unsigned short*)carve((size_t)EE*II*HH*2);
  unsigned short* woutT = (unsigned short*)carve((size_t)EE*HH*II*2);
  size_t estride = (size_t)II*HH;

  // ---- attention block (split-bf16, fp32-accurate) ----
  rmsnorm_kernel<<<TT,256,0,stream>>>(hidden, pre_attn_scale, nullptr, nullptr, hnh, hnl);
  transpose_cvt_split<<<dim3(16,16),256,0,stream>>>(q_w, qkvwTh, qkvwTl, HH, NH*DH);
  transpose_cvt_split<<<dim3(16,4), 256,0,stream>>>(k_w, qkvwTh + (size_t)1024*HH, qkvwTl + (size_t)1024*HH, HH, NKV*DH);
  transpose_cvt_split<<<dim3(16,4), 256,0,stream>>>(v_w, qkvwTh + (size_t)1280*HH, qkvwTl + (size_t)1280*HH, HH, NKV*DH);
  transpose_cvt_split<<<dim3(16,16),256,0,stream>>>(o_w, owTh, owTl, NH*DH, HH);

  // qkv: NY=12 col tiles -> pad grid to 2*128; o: NY=8 -> exactly 128
  mgemm_split<<<2*128,256,0,stream>>>(hnh, hnl, qkvwTh, qkvwTl, qkvb, QKV/128, QKV, HH);

  rope_split_kernel<<<(TT*NH*32+255)/256,256,0,stream>>>(qkvb, QKV, 0, pos, qsh, qsl, NH);
  rope_split_kernel<<<(TT*NKV*32+255)/256,256,0,stream>>>(qkvb, QKV, 1024, pos, ksh, ksl, NKV);
  vt_split_kernel<<<dim3(SS/64,NKV,BB),256,0,stream>>>(qkvb, QKV, 1280, vth, vtl);

  attn_mfma<<<dim3(SS/64,NH,BB),256,0,stream>>>(qsh, qsl, ksh, ksl, vth, vtl, mask, ctxh, ctxl);

  mgemm_split<<<128,256,0,stream>>>(ctxh, ctxl, owTh, owTl, ao, HH/128, HH, NH*DH);
  // fused: xb = hidden + rmsnorm(ao)*post_attn ; hn/hnb = rmsnorm(xb)*pre_moe
  fuse_attn_post<<<TT,256,0,stream>>>(ao, hidden, post_attn_scale, pre_moe_scale, xb, hn, hnb);

  // ---- MoE block (routing fp32, experts bf16) ----
  hipMemsetAsync(counts, 0, 64*sizeof(int), stream);
  hipMemsetAsync(moe, 0, (size_t)TT*HH*sizeof(float), stream);
  route_kernel<<<TT,64,0,stream>>>(hn, gate_w, counts, lists, cw);
  prefix_kernel<<<1,64,0,stream>>>(counts, bases, cw, cw_slot);

  // batched expert-weight transposes (one dispatch per weight tensor)
  transpose_cvt<<<dim3(16,64,EE),256,0,stream>>>(w_in, winT, HH, II, (size_t)HH*II, estride);
  transpose_cvt<<<dim3(16,64,EE),256,0,stream>>>(w_v,  wvT,  HH, II, (size_t)HH*II, estride);
  transpose_cvt<<<dim3(64,16,EE),256,0,stream>>>(w_out, woutT, II, HH, (size_t)II*HH, estride);

  // up: XCD-remapped 1-D grid, 16 row-tiles x 64 (plane|col) x 8 experts
  mgemm<1><<<16*64*EE,256,0,stream>>>(hnb, winT, wvT, estride, nullptr, tmp0, tmp1,
      II, HH, lists, counts, bases);
  moe_combine<<<2*TT,256,0,stream>>>(tmp0, tmp1, cw_slot, bases+EE, ehb);
  // down: XCD-remapped 1-D grid, 16 row-tiles x 16 (col|ksec) x 8 experts, K-split x2
  mgemm<2><<<16*16*EE,256,0,stream>>>(ehb, woutT, nullptr, estride, moe, nullptr, nullptr,
      HH, II, lists, counts, bases);

  // fused: out = xb + rmsnorm(moe)*post_moe
  fuse_moe_post<<<TT,256,0,stream>>>(moe, xb, post_moe_scale, out);
}

// Round 15
// 602.761 us; speedup vs baseline: 1.7721x; 1.0071x over previous
//
#include <hip/hip_runtime.h>
#include <hip/hip_bf16.h>
#include <math.h>

namespace {

constexpr int BB=2, SS=1024, HH=1024, NH=16, NKV=4, DH=64;
constexpr int II=4096, EE=8;
constexpr int TT=BB*SS;
constexpr int QKV=1536;
constexpr float EPS=1e-5f;

typedef __bf16 bf16x8 __attribute__((ext_vector_type(8)));
typedef float f32x4 __attribute__((ext_vector_type(4)));

__device__ __forceinline__ unsigned short f2bf(float x){
  union { float f; unsigned u; } un; un.f = x;
  unsigned r = un.u + 0x7fffu + ((un.u>>16)&1u);
  return (unsigned short)(r>>16);
}
__device__ __forceinline__ float bfval(unsigned short h){
  union { unsigned u; float f; } r; r.u = ((unsigned)h)<<16; return r.f;
}
__device__ __forceinline__ void split2(float v, unsigned short& hi, unsigned short& lo){
  hi = f2bf(v);
  lo = f2bf(v - bfval(hi));
}

__device__ __forceinline__ void gl_lds16(const void* g, void* l){
  __builtin_amdgcn_global_load_lds(
    (const __attribute__((address_space(1))) unsigned int*)g,
    (__attribute__((address_space(3))) unsigned int*)l, 16, 0, 0);
}

__device__ __forceinline__ float gelu_tanh(float x){
  float x3 = x*x*x;
  return 0.5f*x*(1.f + tanhf(0.7978845608028654f*(x + 0.044715f*x3)));
}

// ---------------- RMSNorm: optional fp32 / bf16 / split outputs ----------------
__global__ void rmsnorm_kernel(const float* __restrict__ in, const float* __restrict__ scale,
                               float* __restrict__ outf, unsigned short* __restrict__ outb,
                               unsigned short* __restrict__ outh, unsigned short* __restrict__ outl){
  int row = blockIdx.x, tid = threadIdx.x;
  const float* x = in + (size_t)row*HH;
  float ss = 0.f;
  for (int i=tid;i<HH;i+=256){ float v=x[i]; ss+=v*v; }
  __shared__ float red[256];
  red[tid]=ss; __syncthreads();
  for (int s=128;s>0;s>>=1){ if(tid<s) red[tid]+=red[tid+s]; __syncthreads(); }
  float inv = rsqrtf(red[0]/(float)HH + EPS);
  for (int i=tid;i<HH;i+=256){
    float v = x[i]*inv*scale[i];
    size_t o = (size_t)row*HH+i;
    if (outf) outf[o]=v;
    if (outb) outb[o]=f2bf(v);
    if (outh){ unsigned short h,l; split2(v,h,l); outh[o]=h; outl[o]=l; }
  }
}

// xb = hidden + rmsnorm(ao_raw)*post_scale ; hn/hnb = rmsnorm(xb)*pre_scale
__global__ void fuse_attn_post(const float* __restrict__ ao_raw, const float* __restrict__ hidden,
                               const float* __restrict__ post_scale, const float* __restrict__ pre_scale,
                               float* __restrict__ xb, float* __restrict__ hn,
                               unsigned short* __restrict__ hnb){
  int row = blockIdx.x, tid = threadIdx.x;
  const float* a = ao_raw + (size_t)row*HH;
  const float* h = hidden + (size_t)row*HH;
  float av[4], hv[4];
  float ss = 0.f;
#pragma unroll
  for (int i=0;i<4;i++){
    int idx = tid + i*256;
    av[i]=a[idx]; hv[i]=h[idx];
    ss += av[i]*av[i];
  }
  __shared__ float red[256];
  red[tid]=ss; __syncthreads();
  for (int s=128;s>0;s>>=1){ if(tid<s) red[tid]+=red[tid+s]; __syncthreads(); }
  float inv1 = rsqrtf(red[0]/(float)HH + EPS);
  __syncthreads();
  float xv[4]; float ss2=0.f;
#pragma unroll
  for (int i=0;i<4;i++){
    int idx = tid + i*256;
    xv[i] = hv[i] + av[i]*inv1*post_scale[idx];
    ss2 += xv[i]*xv[i];
  }
  red[tid]=ss2; __syncthreads();
  for (int s=128;s>0;s>>=1){ if(tid<s) red[tid]+=red[tid+s]; __syncthreads(); }
  float inv2 = rsqrtf(red[0]/(float)HH + EPS);
#pragma unroll
  for (int i=0;i<4;i++){
    int idx = tid + i*256;
    size_t o = (size_t)row*HH + idx;
    xb[o] = xv[i];
    float v = xv[i]*inv2*pre_scale[idx];
    hn[o] = v;
    hnb[o] = f2bf(v);
  }
}

// out = xb + rmsnorm(moe)*scale
__global__ void fuse_moe_post(const float* __restrict__ moe, const float* __restrict__ xb,
                              const float* __restrict__ scale, float* __restrict__ out){
  int row = blockIdx.x, tid = threadIdx.x;
  const float* m = moe + (size_t)row*HH;
  float mv[4]; float ss=0.f;
#pragma unroll
  for (int i=0;i<4;i++){
    int idx = tid + i*256;
    mv[i]=m[idx]; ss += mv[i]*mv[i];
  }
  __shared__ float red[256];
  red[tid]=ss; __syncthreads();
  for (int s=128;s>0;s>>=1){ if(tid<s) red[tid]+=red[tid+s]; __syncthreads(); }
  float inv = rsqrtf(red[0]/(float)HH + EPS);
#pragma unroll
  for (int i=0;i<4;i++){
    int idx = tid + i*256;
    size_t o = (size_t)row*HH + idx;
    out[o] = xb[o] + mv[i]*inv*scale[idx];
  }
}

// ---------------- RoPE from merged proj buffer -> split bf16 planes ----------------
__global__ void rope_split_kernel(const float* __restrict__ x, int stride, int off,
                                  const int* __restrict__ pos_ids,
                                  unsigned short* __restrict__ oh, unsigned short* __restrict__ ol,
                                  int nheads){
  int idx = blockIdx.x*256 + threadIdx.x;
  int total = TT*nheads*32;
  if (idx >= total) return;
  int j = idx & 31;
  int hh = (idx>>5) % nheads;
  int t = idx / (32*nheads);
  float pos = (float)pos_ids[t];
  float inv_freq = powf(10000.f, -(float)j/32.f);
  float ang = pos * inv_freq;
  float s, c; sincosf(ang, &s, &c);
  const float* p = x + (size_t)t*stride + off + hh*DH;
  float x1 = p[j], x2 = p[j+32];
  float r1 = x1*c - x2*s;
  float r2 = x2*c + x1*s;
  size_t o = ((size_t)t*nheads + hh)*DH;
  unsigned short h1,l1,h2,l2;
  split2(r1,h1,l1); split2(r2,h2,l2);
  oh[o+j]=h1;    ol[o+j]=l1;
  oh[o+j+32]=h2; ol[o+j+32]=l2;
}

// ---------------- V transpose (from merged proj) -> split bf16 Vt[b][kvh][d][S] ----------------
__global__ __launch_bounds__(256) void vt_split_kernel(const float* __restrict__ src, int stride, int off,
    unsigned short* __restrict__ vth, unsigned short* __restrict__ vtl){
  int k0 = blockIdx.x*64;
  int kvh = blockIdx.y;
  int b = blockIdx.z;
  __shared__ float tile[64][65];
  int t = threadIdx.x;
  int c4 = (t&15)*4, gg = t>>4;
#pragma unroll
  for (int r=0;r<4;r++){
    int kk = gg + r*16;
    float4 v = *reinterpret_cast<const float4*>(src + (size_t)(b*SS+k0+kk)*stride + off + kvh*DH + c4);
    tile[kk][c4]=v.x; tile[kk][c4+1]=v.y; tile[kk][c4+2]=v.z; tile[kk][c4+3]=v.w;
  }
  __syncthreads();
#pragma unroll
  for (int r=0;r<4;r++){
    int dd = gg + r*16;
    ushort4 h4, l4v;
    split2(tile[c4  ][dd], h4.x, l4v.x);
    split2(tile[c4+1][dd], h4.y, l4v.y);
    split2(tile[c4+2][dd], h4.z, l4v.z);
    split2(tile[c4+3][dd], h4.w, l4v.w);
    size_t o = ((size_t)(b*NKV+kvh)*DH + dd)*SS + k0 + c4;
    *reinterpret_cast<ushort4*>(vth+o)=h4;
    *reinterpret_cast<ushort4*>(vtl+o)=l4v;
  }
}

// ---------------- MFMA flash attention (split-bf16, fp32-accurate) ----------------
__global__ __launch_bounds__(256) void attn_mfma(
    const unsigned short* __restrict__ qh, const unsigned short* __restrict__ ql,
    const unsigned short* __restrict__ khp, const unsigned short* __restrict__ klp,
    const unsigned short* __restrict__ vth, const unsigned short* __restrict__ vtl,
    const int* __restrict__ amask,
    unsigned short* __restrict__ ctxh, unsigned short* __restrict__ ctxl)
{
  int qb = blockIdx.x, h = blockIdx.y, b = blockIdx.z;
  int kvh = h >> 2;
  int tid = threadIdx.x;
  int w = tid >> 6, lane = tid & 63;
  int g = lane >> 4, l15 = lane & 15;

  __shared__ __align__(16) unsigned short Klh[64*64];
  __shared__ __align__(16) unsigned short Kll[64*64];
  __shared__ __align__(16) unsigned short Vlh[64*64];
  __shared__ __align__(16) unsigned short Vll[64*64];
  __shared__ __align__(16) unsigned short Pst[4][2][16*72];

  int q0w = qb*64 + w*16;

  bf16x8 qfh[2], qfl[2];
  {
    size_t qrow = ((size_t)(b*SS + q0w + l15)*NH + h)*DH;
#pragma unroll
    for (int ks=0; ks<2; ks++){
      qfh[ks] = *reinterpret_cast<const bf16x8*>(qh + qrow + ks*32 + g*8);
      qfl[ks] = *reinterpret_cast<const bf16x8*>(ql + qrow + ks*32 + g*8);
    }
  }

  f32x4 acc[4];
  float m_run[4], l_run[4];
#pragma unroll
  for (int i=0;i<4;i++){ acc[i]=f32x4{0,0,0,0}; m_run[i]=-1e30f; l_run[i]=0.f; }

  int nkv = qb + 1;
  for (int kblk=0; kblk<nkv; kblk++){
    int k0 = kblk*64;
    __syncthreads();
#pragma unroll
    for (int shot=0; shot<2; shot++){
      int a = shot*256 + tid;
      int row = a>>3, seg = a&7;
      int ss8 = (seg ^ (row&7))*8;
      int lo = row*64 + seg*8;
      size_t kg = ((size_t)(b*SS + k0 + row)*NKV + kvh)*DH + ss8;
      size_t vg = ((size_t)(b*NKV + kvh)*DH + row)*SS + k0 + ss8;
      gl_lds16(khp + kg, Klh + lo);
      gl_lds16(klp + kg, Kll + lo);
      gl_lds16(vth + vg, Vlh + lo);
      gl_lds16(vtl + vg, Vll + lo);
    }
    __syncthreads();

    f32x4 sf[4];
#pragma unroll
    for (int nf=0;nf<4;nf++) sf[nf]=f32x4{0,0,0,0};
#pragma unroll
    for (int ks=0; ks<2; ks++){
#pragma unroll
      for (int nf=0; nf<4; nf++){
        int krow = nf*16 + l15;
        int off = krow*64 + (((ks*4+g) ^ (krow&7))*8);
        bf16x8 bh = *reinterpret_cast<const bf16x8*>(Klh + off);
        bf16x8 bl = *reinterpret_cast<const bf16x8*>(Kll + off);
        sf[nf] = __builtin_amdgcn_mfma_f32_16x16x32_bf16(qfh[ks], bh, sf[nf],0,0,0);
        sf[nf] = __builtin_amdgcn_mfma_f32_16x16x32_bf16(qfh[ks], bl, sf[nf],0,0,0);
        sf[nf] = __builtin_amdgcn_mfma_f32_16x16x32_bf16(qfl[ks], bh, sf[nf],0,0,0);
      }
    }

    int am4[4];
#pragma unroll
    for (int nf=0;nf<4;nf++) am4[nf] = amask[b*SS + k0 + nf*16 + l15];
#pragma unroll
    for (int nf=0;nf<4;nf++){
      int k_abs = k0 + nf*16 + l15;
#pragma unroll
      for (int r=0;r<4;r++){
        float s = sf[nf][r]*0.125f;
        int q_abs = q0w + g*4 + r;
        if (k_abs > q_abs || am4[nf] <= 0) s = -1e9f;
        sf[nf][r] = s;
      }
    }

    float m_new[4], fsc[4];
#pragma unroll
    for (int r=0;r<4;r++){
      float v = fmaxf(fmaxf(sf[0][r],sf[1][r]), fmaxf(sf[2][r],sf[3][r]));
#pragma unroll
      for (int o=1;o<16;o<<=1) v = fmaxf(v, __shfl_xor(v,o));
      m_new[r] = fmaxf(m_run[r], v);
      fsc[r] = expf(m_run[r] - m_new[r]);
      m_run[r] = m_new[r];
    }

    unsigned short* Ph  = Pst[w][0];
    unsigned short* Plo = Pst[w][1];
    float rsum[4] = {0.f,0.f,0.f,0.f};
#pragma unroll
    for (int nf=0;nf<4;nf++){
#pragma unroll
      for (int r=0;r<4;r++){
        float p = expf(sf[nf][r] - m_new[r]);
        rsum[r] += p;
        unsigned short hi = f2bf(p);
        float lo = p - bfval(hi);
        Ph [(g*4+r)*72 + nf*16 + l15] = hi;
        Plo[(g*4+r)*72 + nf*16 + l15] = f2bf(lo);
      }
    }
#pragma unroll
    for (int r=0;r<4;r++){
#pragma unroll
      for (int o=1;o<16;o<<=1) rsum[r] += __shfl_xor(rsum[r],o);
      l_run[r] = l_run[r]*fsc[r] + rsum[r];
#pragma unroll
      for (int nf=0;nf<4;nf++) acc[nf][r] *= fsc[r];
    }

#pragma unroll
    for (int ks=0; ks<2; ks++){
      bf16x8 pa = *reinterpret_cast<const bf16x8*>(Ph  + l15*72 + ks*32 + g*8);
      bf16x8 pl = *reinterpret_cast<const bf16x8*>(Plo + l15*72 + ks*32 + g*8);
#pragma unroll
      for (int nf=0; nf<4; nf++){
        int drow = nf*16 + l15;
        int off = drow*64 + (((ks*4+g) ^ (drow&7))*8);
        bf16x8 vh = *reinterpret_cast<const bf16x8*>(Vlh + off);
        bf16x8 vl = *reinterpret_cast<const bf16x8*>(Vll + off);
        acc[nf] = __builtin_amdgcn_mfma_f32_16x16x32_bf16(pa, vh, acc[nf],0,0,0);
        acc[nf] = __builtin_amdgcn_mfma_f32_16x16x32_bf16(pa, vl, acc[nf],0,0,0);
        acc[nf] = __builtin_amdgcn_mfma_f32_16x16x32_bf16(pl, vh, acc[nf],0,0,0);
      }
    }
  }

#pragma unroll
  for (int r=0;r<4;r++){
    float inv = 1.f / l_run[r];
    size_t orow = ((size_t)(b*SS + q0w + g*4 + r)*NH + h)*DH;
#pragma unroll
    for (int nf=0;nf<4;nf++){
      float v = acc[nf][r]*inv;
      unsigned short hi,lo; split2(v,hi,lo);
      ctxh[orow + nf*16 + l15] = hi;
      ctxl[orow + nf*16 + l15] = lo;
    }
  }
}

// ---------------- MoE routing ----------------
__global__ void route_kernel(const float* __restrict__ x, const float* __restrict__ gw,
                             int* __restrict__ counts, int* __restrict__ lists,
                             float* __restrict__ cw){
  int t = blockIdx.x;
  int lane = threadIdx.x;
  float acc[EE];
#pragma unroll
  for (int e=0;e<EE;e++) acc[e]=0.f;
  for (int hh=lane; hh<HH; hh+=64){
    float xv = x[(size_t)t*HH + hh];
#pragma unroll
    for (int e=0;e<EE;e++) acc[e] += xv*gw[hh*EE+e];
  }
#pragma unroll
  for (int e=0;e<EE;e++){
#pragma unroll
    for (int off=1; off<64; off<<=1) acc[e] += __shfl_xor(acc[e], off);
  }
  if (lane==0){
    float m = acc[0];
    for (int e=1;e<EE;e++) m = fmaxf(m, acc[e]);
    float p[EE], s=0.f;
    for (int e=0;e<EE;e++){ p[e]=expf(acc[e]-m); s+=p[e]; }
    float invs = 1.f/s;
    for (int e=0;e<EE;e++) p[e]*=invs;
    int i1=0;
    for (int e=1;e<EE;e++) if (p[e]>p[i1]) i1=e;
    int i2 = (i1==0)?1:0;
    for (int e=0;e<EE;e++) if (e!=i1 && p[e]>p[i2]) i2=e;
    int pos = atomicAdd(&counts[i1],1);
    lists[i1*TT+pos]=t; cw[i1*TT+pos]=p[i1];
    pos = atomicAdd(&counts[i2],1);
    lists[i2*TT+pos]=t; cw[i2*TT+pos]=p[i2];
  }
}

// prefix over experts + slot-indexed gate weights; bases[EE] = total
__global__ void prefix_kernel(const int* __restrict__ c, int* __restrict__ b,
                              const float* __restrict__ cw, float* __restrict__ cw_slot){
  int lane = threadIdx.x;
  __shared__ int sb[EE+1];
  if (lane==0){
    int s=0;
    for (int e=0;e<EE;e++){ sb[e]=s; b[e]=s; s+=c[e]; }
    sb[EE]=s; b[EE]=s;
  }
  __syncthreads();
  for (int e=0;e<EE;e++){
    int cnt=c[e], base=sb[e];
    for (int i=lane;i<cnt;i+=64) cw_slot[base+i]=cw[e*TT+i];
  }
}

// ehb = bf16( gelu(tmp0) * tmp1 * cw_slot[row] )
__global__ void moe_combine(const unsigned short* __restrict__ t0,
                            const unsigned short* __restrict__ t1,
                            const float* __restrict__ cwslot,
                            const int* __restrict__ ntotp,
                            unsigned short* __restrict__ ehb){
  int row = blockIdx.x;
  if (row >= *ntotp) return;
  float c = cwslot[row];
  size_t base = (size_t)row*II;
  int tid = threadIdx.x;
  for (int c0 = tid*8; c0 < II; c0 += 256*8){
    ushort4 x0 = *reinterpret_cast<const ushort4*>(t0+base+c0);
    ushort4 x1 = *reinterpret_cast<const ushort4*>(t0+base+c0+4);
    ushort4 y0 = *reinterpret_cast<const ushort4*>(t1+base+c0);
    ushort4 y1 = *reinterpret_cast<const ushort4*>(t1+base+c0+4);
    ushort4 o0, o1;
    o0.x = f2bf(gelu_tanh(bfval(x0.x))*bfval(y0.x)*c);
    o0.y = f2bf(gelu_tanh(bfval(x0.y))*bfval(y0.y)*c);
    o0.z = f2bf(gelu_tanh(bfval(x0.z))*bfval(y0.z)*c);
    o0.w = f2bf(gelu_tanh(bfval(x0.w))*bfval(y0.w)*c);
    o1.x = f2bf(gelu_tanh(bfval(x1.x))*bfval(y1.x)*c);
    o1.y = f2bf(gelu_tanh(bfval(x1.y))*bfval(y1.y)*c);
    o1.z = f2bf(gelu_tanh(bfval(x1.z))*bfval(y1.z)*c);
    o1.w = f2bf(gelu_tanh(bfval(x1.w))*bfval(y1.w)*c);
    *reinterpret_cast<ushort4*>(ehb+base+c0)   = o0;
    *reinterpret_cast<ushort4*>(ehb+base+c0+4) = o1;
  }
}

// ---------------- transpose + fp32->bf16 (single plane), batched over z ----------------
__global__ __launch_bounds__(256) void transpose_cvt(const float* __restrict__ in,
    unsigned short* __restrict__ out, int K, int N, size_t in_zstride, size_t out_zstride){
  __shared__ float tile[64][65];
  int k0 = blockIdx.x*64, n0 = blockIdx.y*64;
  const float* inz = in + in_zstride*blockIdx.z;
  unsigned short* outz = out + out_zstride*blockIdx.z;
  int t = threadIdx.x;
  int c4 = (t&15)*4, g = t>>4;
#pragma unroll
  for (int r=0;r<4;r++){
    int kk = g + r*16;
    float4 v = *reinterpret_cast<const float4*>(inz + (size_t)(k0+kk)*N + n0 + c4);
    tile[kk][c4]=v.x; tile[kk][c4+1]=v.y; tile[kk][c4+2]=v.z; tile[kk][c4+3]=v.w;
  }
  __syncthreads();
#pragma unroll
  for (int r=0;r<4;r++){
    int nn = g + r*16;
    ushort4 o;
    o.x=f2bf(tile[c4][nn]);   o.y=f2bf(tile[c4+1][nn]);
    o.z=f2bf(tile[c4+2][nn]); o.w=f2bf(tile[c4+3][nn]);
    *reinterpret_cast<ushort4*>(outz + (size_t)(n0+nn)*K + k0 + c4) = o;
  }
}

// ---------------- transpose + split hi/lo ----------------
__global__ __launch_bounds__(256) void transpose_cvt_split(const float* __restrict__ in,
    unsigned short* __restrict__ oh, unsigned short* __restrict__ ol, int K, int N){
  __shared__ float tile[64][65];
  int k0 = blockIdx.x*64, n0 = blockIdx.y*64;
  int t = threadIdx.x;
  int c4 = (t&15)*4, g = t>>4;
#pragma unroll
  for (int r=0;r<4;r++){
    int kk = g + r*16;
    float4 v = *reinterpret_cast<const float4*>(in + (size_t)(k0+kk)*N + n0 + c4);
    tile[kk][c4]=v.x; tile[kk][c4+1]=v.y; tile[kk][c4+2]=v.z; tile[kk][c4+3]=v.w;
  }
  __syncthreads();
#pragma unroll
  for (int r=0;r<4;r++){
    int nn = g + r*16;
    ushort4 h4, l4v;
    split2(tile[c4  ][nn], h4.x, l4v.x);
    split2(tile[c4+1][nn], h4.y, l4v.y);
    split2(tile[c4+2][nn], h4.z, l4v.z);
    split2(tile[c4+3][nn], h4.w, l4v.w);
    size_t o = (size_t)(n0+nn)*K + k0 + c4;
    *reinterpret_cast<ushort4*>(oh + o) = h4;
    *reinterpret_cast<ushort4*>(ol + o) = l4v;
  }
}

// ---------------- split-bf16 3-term MFMA GEMM, dbuf, XCD-remapped grid, swizzled LDS ----------------
__global__ __launch_bounds__(256,2) void mgemm_split(
    const unsigned short* __restrict__ Ah, const unsigned short* __restrict__ Alo,
    const unsigned short* __restrict__ Bh, const unsigned short* __restrict__ Blo,
    float* __restrict__ Cf, int NY, int N, int K)
{
  int bid = blockIdx.x;
  int qq = bid >> 7, rr = bid & 127;
  int xti = rr >> 3, sbit = rr & 7;
  int g = qq*8 + sbit;
  if (g >= NY) return;
  int row0 = xti*128, col0 = g*128;
  __shared__ __align__(16) unsigned short lds[32768];

  int t = threadIdx.x;
  int lane = t&63, w = t>>6, wr = w>>1, wc = w&1;
  int sr = t>>2, seg = t&3;
  int swzs = (t>>3)&3;

  f32x4 acc[4][4];
#pragma unroll
  for (int m=0;m<4;m++)
#pragma unroll
    for (int n=0;n<4;n++) acc[m][n]=f32x4{0,0,0,0};

  int l15 = lane&15, l4 = lane>>4;
  int swzr = (l15>>1)&3;

  auto stage = [&](int buf, int k0){
    unsigned short* Lb = lds + buf*16384;
    int ksw = (seg ^ swzs)*8;
#pragma unroll
    for (int i=0;i<2;i++){
      int ldso = (sr + i*64)*32 + seg*8;
      size_t ar = (size_t)(row0 + sr + i*64);
      size_t br = (size_t)(col0 + sr + i*64);
      gl_lds16(Ah  + ar*K + k0 + ksw, Lb +         ldso);
      gl_lds16(Alo + ar*K + k0 + ksw, Lb + 4096  + ldso);
      gl_lds16(Bh  + br*K + k0 + ksw, Lb + 8192  + ldso);
      gl_lds16(Blo + br*K + k0 + ksw, Lb + 12288 + ldso);
    }
  };

  stage(0, 0);
  __syncthreads();
  int cur = 0;
  int NIT = K/32;
  int cofs = (l4 ^ swzr)*8;
  for (int it=0; it<NIT; it++){
    if (it+1 < NIT) stage(cur^1, (it+1)*32);
    const unsigned short* Lb = lds + cur*16384;
    bf16x8 ah[4], al[4], bh[4], bl[4];
#pragma unroll
    for (int m=0;m<4;m++){
      int ro = (wr*64 + m*16 + l15)*32 + cofs;
      ah[m]=*reinterpret_cast<const bf16x8*>(Lb +        ro);
      al[m]=*reinterpret_cast<const bf16x8*>(Lb + 4096 + ro);
    }
#pragma unroll
    for (int n=0;n<4;n++){
      int ro = (wc*64 + n*16 + l15)*32 + cofs;
      bh[n]=*reinterpret_cast<const bf16x8*>(Lb + 8192  + ro);
      bl[n]=*reinterpret_cast<const bf16x8*>(Lb + 12288 + ro);
    }
#pragma unroll
    for (int m=0;m<4;m++)
#pragma unroll
      for (int n=0;n<4;n++){
        acc[m][n] = __builtin_amdgcn_mfma_f32_16x16x32_bf16(ah[m], bh[n], acc[m][n], 0,0,0);
        acc[m][n] = __builtin_amdgcn_mfma_f32_16x16x32_bf16(ah[m], bl[n], acc[m][n], 0,0,0);
        acc[m][n] = __builtin_amdgcn_mfma_f32_16x16x32_bf16(al[m], bh[n], acc[m][n], 0,0,0);
      }
    __syncthreads();
    cur ^= 1;
  }

#pragma unroll
  for (int m=0;m<4;m++){
    int rb = wr*64 + m*16 + l4*4;
#pragma unroll
    for (int n=0;n<4;n++){
      int col = col0 + wc*64 + n*16 + l15;
#pragma unroll
      for (int r=0;r<4;r++){
        int row = row0 + rb + r;
        Cf[(size_t)row*N + col] = acc[m][n][r];
      }
    }
  }
}

// ---------------- MoE up-GEMM: 128x256 tile, 4 waves (each 128x64), counted-vmcnt ----------------
// grid 1-D 16*32*EE remapped: bid = qq*128 + xti*8 + sbit; g = qq*8+sbit = y + 32*e;
// y parity = plane (w_in/w_v), y>>1 = col tile (256 wide).
__global__ __launch_bounds__(256,2) void mgemm_up(
    const unsigned short* __restrict__ A, const unsigned short* __restrict__ B0b,
    const unsigned short* __restrict__ B1b, size_t bstride,
    unsigned short* __restrict__ Cb0, unsigned short* __restrict__ Cb1,
    const int* __restrict__ listb,
    const int* __restrict__ countb, const int* __restrict__ basep)
{
  int bid = blockIdx.x;
  int qq = bid >> 7, rr = bid & 127;
  int xti = rr >> 3, sbit = rr & 7;
  int g = qq*8 + sbit;
  int y = g & 31, e = g >> 5;

  int M = countb[e];
  int row0 = xti*128;
  if (row0 >= M) return;
  int which = y & 1;
  int col0 = (y >> 1)*256;
  const unsigned short* B = (which ? B1b : B0b) + bstride*e;
  int slot = basep[e];
  const int* rowlist = listb + e*TT;

  // 3 bufs x (A[128][32]=8KB + B[256][32]=16KB) = 72 KB
  __shared__ __align__(16) unsigned short lds[3][12288];

  int t = threadIdx.x;
  int lane = t&63, w = t>>6;
  int sr = t>>2, seg = t&3;
  int swzs = (t>>3)&3;

  size_t arow[2], brow[4];
#pragma unroll
  for (int i=0;i<2;i++){
    int r = row0 + sr + i*64;
    int rc = (r < M) ? r : (M-1);
    arow[i] = (size_t)rowlist[rc];
  }
#pragma unroll
  for (int i=0;i<4;i++)
    brow[i] = (size_t)(col0 + sr + i*64);

  f32x4 acc[8][4];
#pragma unroll
  for (int m=0;m<8;m++)
#pragma unroll
    for (int n=0;n<4;n++) acc[m][n]=f32x4{0,0,0,0};

  int l15 = lane&15, l4 = lane>>4;
  int cofs = (l4 ^ ((l15>>1)&3))*8;

  auto stage = [&](int buf, int k0){
    int ksw = (seg ^ swzs)*8;
#pragma unroll
    for (int i=0;i<2;i++){
      int ldso = (sr + i*64)*32 + seg*8;
      gl_lds16(A + arow[i]*HH + k0 + ksw, &lds[buf][0] + ldso);
    }
#pragma unroll
    for (int i=0;i<4;i++){
      int ldso = 4096 + (sr + i*64)*32 + seg*8;
      gl_lds16(B + brow[i]*HH + k0 + ksw, &lds[buf][0] + ldso);
    }
  };

  constexpr int NIT = HH/32;
  stage(0, 0);
  stage(1, 32);

  for (int it=0; it<NIT; it++){
    if (it+1 < NIT) asm volatile("s_waitcnt vmcnt(6)" ::: "memory");
    else            asm volatile("s_waitcnt vmcnt(0)" ::: "memory");
    __builtin_amdgcn_s_barrier();
    if (it+2 < NIT) stage((it+2)%3, (it+2)*32);

    const unsigned short* La = &lds[it%3][0];
    const unsigned short* Lb = La + 4096;
    bf16x8 af[8], bf[4];
#pragma unroll
    for (int m=0;m<8;m++)
      af[m] = *reinterpret_cast<const bf16x8*>(La + (m*16 + l15)*32 + cofs);
#pragma unroll
    for (int n=0;n<4;n++)
      bf[n] = *reinterpret_cast<const bf16x8*>(Lb + (w*64 + n*16 + l15)*32 + cofs);
#pragma unroll
    for (int m=0;m<8;m++)
#pragma unroll
      for (int n=0;n<4;n++)
        acc[m][n] = __builtin_amdgcn_mfma_f32_16x16x32_bf16(af[m], bf[n], acc[m][n], 0,0,0);
  }

  unsigned short* Cb = which ? Cb1 : Cb0;
#pragma unroll
  for (int m=0;m<8;m++){
    int rb = m*16 + l4*4;
#pragma unroll
    for (int n=0;n<4;n++){
      int col = col0 + w*64 + n*16 + l15;
#pragma unroll
      for (int r=0;r<4;r++){
        int row = row0 + rb + r;
        if (row >= M) continue;
        Cb[(size_t)(slot+row)*II + col] = f2bf(acc[m][n][r]);
      }
    }
  }
}

// ---------------- MoE down-GEMM (MODE 2 of old mgemm), BK=32, counted-vmcnt ----------------
__global__ __launch_bounds__(256,3) void mgemm_down(
    const unsigned short* __restrict__ A, const unsigned short* __restrict__ B0b,
    size_t bstride, float* __restrict__ Cf,
    const int* __restrict__ listb,
    const int* __restrict__ countb, const int* __restrict__ basep)
{
  int bid = blockIdx.x;
  int qq = bid >> 7, rr = bid & 127;
  int xti = rr >> 3, sbit = rr & 7;
  int g = qq*8 + sbit;
  int y = g & 15, e = g >> 4;

  int M = countb[e];
  int row0 = xti*128;
  if (row0 >= M) return;
  int col0 = (y & 7)*128;
  int kbase = (y >> 3)*(II/2);
  int KL = II/2;
  const unsigned short* B = B0b + bstride*e;
  int slot = basep[e];
  const int* rowlist = listb + e*TT;

  __shared__ __align__(16) unsigned short lds[3][2][4096];

  int t = threadIdx.x;
  int lane = t&63, w = t>>6, wr = w>>1, wc = w&1;
  int sr = t>>2, seg = t&3;
  int swzs = (t>>3)&3;

  size_t arow[2], brow[2];
#pragma unroll
  for (int i=0;i<2;i++){
    int r = row0 + sr + i*64;
    int rc = (r < M) ? r : (M-1);
    arow[i] = (size_t)(slot + rc);
    brow[i] = (size_t)(col0 + sr + i*64);
  }

  f32x4 acc[4][4];
#pragma unroll
  for (int m=0;m<4;m++)
#pragma unroll
    for (int n=0;n<4;n++) acc[m][n]=f32x4{0,0,0,0};

  int l15 = lane&15, l4 = lane>>4;
  int cofs = (l4 ^ ((l15>>1)&3))*8;

  auto stage = [&](int buf, int k0){
    int ksw = (seg ^ swzs)*8;
#pragma unroll
    for (int i=0;i<2;i++){
      int ldso = (sr + i*64)*32 + seg*8;
      gl_lds16(A + arow[i]*II + kbase + k0 + ksw, &lds[buf][0][0] + ldso);
      gl_lds16(B + brow[i]*II + kbase + k0 + ksw, &lds[buf][1][0] + ldso);
    }
  };

  int NIT = KL/32;
  stage(0, 0);
  stage(1, 32);

  for (int it=0; it<NIT; it++){
    if (it+1 < NIT) asm volatile("s_waitcnt vmcnt(4)" ::: "memory");
    else            asm volatile("s_waitcnt vmcnt(0)" ::: "memory");
    __builtin_amdgcn_s_barrier();
    if (it+2 < NIT) stage((it+2)%3, (it+2)*32);

    int cb = it%3;
    const unsigned short* La = &lds[cb][0][0];
    const unsigned short* Lb = &lds[cb][1][0];
    bf16x8 af[4], bf[4];
#pragma unroll
    for (int m=0;m<4;m++)
      af[m] = *reinterpret_cast<const bf16x8*>(La + (wr*64 + m*16 + l15)*32 + cofs);
#pragma unroll
    for (int n=0;n<4;n++)
      bf[n] = *reinterpret_cast<const bf16x8*>(Lb + (wc*64 + n*16 + l15)*32 + cofs);
#pragma unroll
    for (int m=0;m<4;m++)
#pragma unroll
      for (int n=0;n<4;n++)
        acc[m][n] = __builtin_amdgcn_mfma_f32_16x16x32_bf16(af[m], bf[n], acc[m][n], 0,0,0);
  }

#pragma unroll
  for (int m=0;m<4;m++){
    int rb = wr*64 + m*16 + l4*4;
#pragma unroll
    for (int n=0;n<4;n++){
      int col = col0 + wc*64 + n*16 + l15;
#pragma unroll
      for (int r=0;r<4;r++){
        int row = row0 + rb + r;
        if (row >= M) continue;
        atomicAdd(&Cf[(size_t)rowlist[row]*HH + col], acc[m][n][r]);
      }
    }
  }
}

} // namespace

extern "C" void kernel_launch(void* const* d_in, const int* in_sizes, int n_in,
                              void* d_out, int out_size, void* d_ws, size_t ws_size,
                              hipStream_t stream) {
  const float* hidden = (const float*)d_in[0];
  const int*   mask   = (const int*)d_in[1];
  const int*   pos    = (const int*)d_in[2];
  const float* q_w    = (const float*)d_in[3];
  const float* k_w    = (const float*)d_in[4];
  const float* v_w    = (const float*)d_in[5];
  const float* o_w    = (const float*)d_in[6];
  const float* pre_attn_scale  = (const float*)d_in[7];
  const float* post_attn_scale = (const float*)d_in[8];
  const float* pre_moe_scale   = (const float*)d_in[9];
  const float* post_moe_scale  = (const float*)d_in[10];
  const float* gate_w = (const float*)d_in[11];
  const float* w_in   = (const float*)d_in[12];
  const float* w_v    = (const float*)d_in[13];
  const float* w_out  = (const float*)d_in[14];
  float* out = (float*)d_out;

  char* base = (char*)d_ws;
  auto carve = [&](size_t bytes)->char*{
    char* r = base; base += (bytes + 255) & ~(size_t)255; return r;
  };
  float* hn  = (float*)carve((size_t)TT*HH*4);
  unsigned short* hnb = (unsigned short*)carve((size_t)TT*HH*2);
  unsigned short* hnh = (unsigned short*)carve((size_t)TT*HH*2);
  unsigned short* hnl = (unsigned short*)carve((size_t)TT*HH*2);
  float* qkvb = (float*)carve((size_t)TT*QKV*4);
  unsigned short* qsh = (unsigned short*)carve((size_t)TT*NH*DH*2);
  unsigned short* qsl = (unsigned short*)carve((size_t)TT*NH*DH*2);
  unsigned short* ksh = (unsigned short*)carve((size_t)TT*NKV*DH*2);
  unsigned short* ksl = (unsigned short*)carve((size_t)TT*NKV*DH*2);
  unsigned short* vth = (unsigned short*)carve((size_t)TT*NKV*DH*2);
  unsigned short* vtl = (unsigned short*)carve((size_t)TT*NKV*DH*2);
  unsigned short* ctxh = (unsigned short*)carve((size_t)TT*NH*DH*2);
  unsigned short* ctxl = (unsigned short*)carve((size_t)TT*NH*DH*2);
  float* ao  = (float*)carve((size_t)TT*HH*4);
  float* xb  = (float*)carve((size_t)TT*HH*4);
  float* moe = (float*)carve((size_t)TT*HH*4);
  float* cw  = (float*)carve((size_t)EE*TT*4);
  float* cw_slot = (float*)carve((size_t)2*TT*4);
  int* counts = (int*)carve(64*4);
  int* bases  = (int*)carve(64*4);
  int* lists  = (int*)carve((size_t)EE*TT*4);
  unsigned short* qkvwTh = (unsigned short*)carve((size_t)QKV*HH*2);
  unsigned short* qkvwTl = (unsigned short*)carve((size_t)QKV*HH*2);
  unsigned short* owTh = (unsigned short*)carve((size_t)NH*DH*HH*2);
  unsigned short* owTl = (unsigned short*)carve((size_t)NH*DH*HH*2);
  unsigned short* ehb   = (unsigned short*)carve((size_t)2*TT*II*2);
  unsigned short* tmp0  = (unsigned short*)carve((size_t)2*TT*II*2);
  unsigned short* tmp1  = (unsigned short*)carve((size_t)2*TT*II*2);
  unsigned short* winT  = (unsigned short*)carve((size_t)EE*II*HH*2);
  unsigned short* wvT   = (unsigned short*)carve((size_t)EE*II*HH*2);
  unsigned short* woutT = (unsigned short*)carve((size_t)EE*HH*II*2);
  size_t estride = (size_t)II*HH;

  // ---- attention block (split-bf16, fp32-accurate) ----
  rmsnorm_kernel<<<TT,256,0,stream>>>(hidden, pre_attn_scale, nullptr, nullptr, hnh, hnl);
  transpose_cvt_split<<<dim3(16,16),256,0,stream>>>(q_w, qkvwTh, qkvwTl, HH, NH*DH);
  transpose_cvt_split<<<dim3(16,4), 256,0,stream>>>(k_w, qkvwTh + (size_t)1024*HH, qkvwTl + (size_t)1024*HH, HH, NKV*DH);
  transpose_cvt_split<<<dim3(16,4), 256,0,stream>>>(v_w, qkvwTh + (size_t)1280*HH, qkvwTl + (size_t)1280*HH, HH, NKV*DH);
  transpose_cvt_split<<<dim3(16,16),256,0,stream>>>(o_w, owTh, owTl, NH*DH, HH);

  mgemm_split<<<2*128,256,0,stream>>>(hnh, hnl, qkvwTh, qkvwTl, qkvb, QKV/128, QKV, HH);

  rope_split_kernel<<<(TT*NH*32+255)/256,256,0,stream>>>(qkvb, QKV, 0, pos, qsh, qsl, NH);
  rope_split_kernel<<<(TT*NKV*32+255)/256,256,0,stream>>>(qkvb, QKV, 1024, pos, ksh, ksl, NKV);
  vt_split_kernel<<<dim3(SS/64,NKV,BB),256,0,stream>>>(qkvb, QKV, 1280, vth, vtl);

  attn_mfma<<<dim3(SS/64,NH,BB),256,0,stream>>>(qsh, qsl, ksh, ksl, vth, vtl, mask, ctxh, ctxl);

  mgemm_split<<<128,256,0,stream>>>(ctxh, ctxl, owTh, owTl, ao, HH/128, HH, NH*DH);
  fuse_attn_post<<<TT,256,0,stream>>>(ao, hidden, post_attn_scale, pre_moe_scale, xb, hn, hnb);

  // ---- MoE block (routing fp32, experts bf16) ----
  hipMemsetAsync(counts, 0, 64*sizeof(int), stream);
  hipMemsetAsync(moe, 0, (size_t)TT*HH*sizeof(float), stream);
  route_kernel<<<TT,64,0,stream>>>(hn, gate_w, counts, lists, cw);
  prefix_kernel<<<1,64,0,stream>>>(counts, bases, cw, cw_slot);

  transpose_cvt<<<dim3(16,64,EE),256,0,stream>>>(w_in, winT, HH, II, (size_t)HH*II, estride);
  transpose_cvt<<<dim3(16,64,EE),256,0,stream>>>(w_v,  wvT,  HH, II, (size_t)HH*II, estride);
  transpose_cvt<<<dim3(64,16,EE),256,0,stream>>>(w_out, woutT, II, HH, (size_t)II*HH, estride);

  // up: 128x256 tile, XCD-remapped 1-D grid: 16 row-tiles x 32 (plane|col256) x 8 experts
  mgemm_up<<<16*32*EE,256,0,stream>>>(hnb, winT, wvT, estride, tmp0, tmp1,
      lists, counts, bases);
  moe_combine<<<2*TT,256,0,stream>>>(tmp0, tmp1, cw_slot, bases+EE, ehb);
  // down: 128x128 tile, XCD-remapped, K-split x2
  mgemm_down<<<16*16*EE,256,0,stream>>>(ehb, woutT, estride, moe,
      lists, counts, bases);

  fuse_moe_post<<<TT,256,0,stream>>>(moe, xb, post_moe_scale, out);
}